// Round 1
// baseline (838.159 us; speedup 1.0000x reference)
//
#include <hip/hip_runtime.h>
#include <cstdint>
#include <cstddef>

#define CDIV(a,b) (((a)+(b)-1)/(b))

__device__ __forceinline__ float sgnf(float w){ return (w>0.f)?1.f:((w<0.f)?-1.f:0.f); }

// ---------------- weight binarization ----------------
__global__ void row_absmean(const float* __restrict__ W, float* __restrict__ alpha, int K){
  int r = blockIdx.x;
  const float* wr = W + (size_t)r*K;
  float s = 0.f;
  for (int k = threadIdx.x; k < K; k += blockDim.x) s += fabsf(wr[k]);
  #pragma unroll
  for (int off = 32; off; off >>= 1) s += __shfl_xor(s, off);
  __shared__ float red[8];
  int wid = threadIdx.x >> 6, lane = threadIdx.x & 63;
  if (lane == 0) red[wid] = s;
  __syncthreads();
  if (threadIdx.x == 0){
    float t = 0.f; int nw = blockDim.x >> 6;
    for (int i = 0; i < nw; ++i) t += red[i];
    alpha[r] = t / (float)K;
  }
}

// Bcat1: [1216][256], rows 0..601 = aL[o]*sign(W1l[o][k]); 602..1203 = aR[o]*sign(W1r[o][k-602]); 1204..1215 = 0
__global__ void fill_bcat1(const float* __restrict__ Wl, const float* __restrict__ Wr,
                           const float* __restrict__ aL, const float* __restrict__ aR,
                           float* __restrict__ Bcat){
  int idx = blockIdx.x*blockDim.x + threadIdx.x;
  if (idx >= 1216*256) return;
  int o = idx & 255, k = idx >> 8;
  float v = 0.f;
  if (k < 602)       v = aL[o] * sgnf(Wl[(size_t)o*602 + k]);
  else if (k < 1204) v = aR[o] * sgnf(Wr[(size_t)o*602 + (k-602)]);
  Bcat[idx] = v;
}

// Bcat2: [512][41], rows 0..255 = a2L[o]*sign(W2l[o][k]); 256..511 = a2R[o]*sign(W2r[o][k-256])
__global__ void fill_bcat2(const float* __restrict__ Wl, const float* __restrict__ Wr,
                           const float* __restrict__ aL, const float* __restrict__ aR,
                           float* __restrict__ Bcat){
  int idx = blockIdx.x*blockDim.x + threadIdx.x;
  if (idx >= 512*41) return;
  int o = idx % 41, k = idx / 41;
  float v;
  if (k < 256) v = aL[o] * sgnf(Wl[(size_t)o*256 + k]);
  else         v = aR[o] * sgnf(Wr[(size_t)o*256 + (k-256)]);
  Bcat[idx] = v;
}

// ---------------- sign-pack (norm_bin): one wave per row, 2 bitplanes ----------------
__global__ void pack_sign_kernel(const float* __restrict__ X, uint32_t* __restrict__ P,
                                 int nrows, int ncols, int ngroups, int halfw, int wstride){
  int wpb = blockDim.x >> 6;
  int row = blockIdx.x * wpb + (threadIdx.x >> 6);
  int lane = threadIdx.x & 63;
  if (row >= nrows) return;
  const float* xr = X + (size_t)row * ncols;
  float s = 0.f;
  for (int c = lane; c < ncols; c += 64) s += xr[c];
  #pragma unroll
  for (int off = 32; off; off >>= 1) s += __shfl_xor(s, off);
  float mean = s / (float)ncols;
  uint32_t* pr = P + (size_t)row * wstride;
  for (int g = 0; g < ngroups; ++g){
    int c = g*64 + lane;
    bool valid = c < ncols;
    float d = valid ? (xr[c] - mean) : 0.f;
    unsigned long long bp = __ballot(valid && (d > 0.f));
    unsigned long long bn = __ballot(valid && (d < 0.f));
    if (lane == 0){
      pr[2*g]           = (uint32_t)bp;
      pr[2*g+1]         = (uint32_t)(bp >> 32);
      pr[halfw + 2*g]   = (uint32_t)bn;
      pr[halfw + 2*g+1] = (uint32_t)(bn >> 32);
    }
  }
}

// ---------------- CSR build ----------------
__global__ void zero_i32(int* __restrict__ p, int n){
  int i = blockIdx.x*blockDim.x + threadIdx.x;
  if (i < n) p[i] = 0;
}
__global__ void copy_i32(const int* __restrict__ a, int* __restrict__ b, int n){
  int i = blockIdx.x*blockDim.x + threadIdx.x;
  if (i < n) b[i] = a[i];
}
__global__ void count_deg(const int* __restrict__ dst, int E, int* __restrict__ deg){
  int e = blockIdx.x*blockDim.x + threadIdx.x;
  if (e < E) atomicAdd(&deg[dst[e]], 1);
}
// single-block exclusive scan, 1024 threads
__global__ void scan_kernel(const int* __restrict__ deg, int* __restrict__ rs, int n){
  __shared__ int partial[1024];
  int tid = threadIdx.x;
  int per = CDIV(n, 1024);
  int begin = tid*per; if (begin > n) begin = n;
  int end = begin + per; if (end > n) end = n;
  int s = 0;
  for (int i = begin; i < end; ++i) s += deg[i];
  partial[tid] = s;
  __syncthreads();
  for (int off = 1; off < 1024; off <<= 1){
    int add = (tid >= off) ? partial[tid-off] : 0;
    __syncthreads();
    partial[tid] += add;
    __syncthreads();
  }
  int prefix = (tid == 0) ? 0 : partial[tid-1];
  for (int i = begin; i < end; ++i){ rs[i] = prefix; prefix += deg[i]; }
  if (tid == 1023) rs[n] = prefix;
}
__global__ void fill_csr(const int* __restrict__ src, const int* __restrict__ dst, int E,
                         int* __restrict__ cur, int* __restrict__ esrc){
  int e = blockIdx.x*blockDim.x + threadIdx.x;
  if (e < E){
    int p = atomicAdd(&cur[dst[e]], 1);
    esrc[p] = src[e];
  }
}

// ---------------- per-target segment mean of packed signs ----------------
__global__ void aggregate_kernel(const uint32_t* __restrict__ packed, int wstride, int halfw, int ncols,
                                 const int* __restrict__ rs, const int* __restrict__ esrc,
                                 float* __restrict__ agg){
  int t = blockIdx.x, tid = threadIdx.x;
  int s0 = rs[t], s1 = rs[t+1];
  int acc0 = 0, acc1 = 0, acc2 = 0;
  for (int e = s0; e < s1; ++e){
    const uint32_t* pr = packed + (size_t)esrc[e] * wstride;
    { int f = tid;       if (f < ncols){ int w = f>>5, b = f&31; acc0 += (int)((pr[w]>>b)&1) - (int)((pr[halfw+w]>>b)&1); } }
    { int f = tid + 256; if (f < ncols){ int w = f>>5, b = f&31; acc1 += (int)((pr[w]>>b)&1) - (int)((pr[halfw+w]>>b)&1); } }
    { int f = tid + 512; if (f < ncols){ int w = f>>5, b = f&31; acc2 += (int)((pr[w]>>b)&1) - (int)((pr[halfw+w]>>b)&1); } }
  }
  int deg = s1 - s0;
  float inv = 1.f / (float)(deg > 0 ? deg : 1);
  if (tid < ncols)       agg[(size_t)t*ncols + tid]       = acc0 * inv;
  if (tid + 256 < ncols) agg[(size_t)t*ncols + tid + 256] = acc1 * inv;
  if (tid + 512 < ncols) agg[(size_t)t*ncols + tid + 512] = acc2 * inv;
}

// ---------------- layer-1 GEMM: H = relu([agg1 | sgn_xt] @ Bcat1 + b1) ----------------
// M=11264, N=256, K=1216 (602 f32 + 602 sign-unpacked + 12 zero pad). 64x64 tile, 4x4/thread.
__global__ __launch_bounds__(256) void gemm1_kernel(
    const float* __restrict__ agg1, const uint32_t* __restrict__ packedX,
    const float* __restrict__ Bcat, const float* __restrict__ bias,
    float* __restrict__ H){
  __shared__ __align__(16) float As[16][64];
  __shared__ __align__(16) float Bs[16][64];
  int tid = threadIdx.x;
  int m0 = blockIdx.y * 64, n0 = blockIdx.x * 64;
  int tx = tid & 15, ty = tid >> 4;
  int mr = tid >> 2, kq = (tid & 3) * 4;
  int cB = tid & 63, kB = tid >> 6;
  float acc[4][4] = {};
  for (int k0 = 0; k0 < 1216; k0 += 16){
    int mg = m0 + mr;
    #pragma unroll
    for (int j = 0; j < 4; ++j){
      int kg = k0 + kq + j;
      float v;
      if (kg < 602) v = agg1[(size_t)mg*602 + kg];
      else if (kg < 1204){
        int f = kg - 602; int w = f >> 5, b = f & 31;
        const uint32_t* pr = packedX + (size_t)mg*40;
        v = (float)((pr[w]>>b)&1) - (float)((pr[20+w]>>b)&1);
      } else v = 0.f;
      As[kq+j][mr] = v;
    }
    #pragma unroll
    for (int p = 0; p < 4; ++p){
      int k = kB + p*4;
      Bs[k][cB] = Bcat[(size_t)(k0+k)*256 + n0 + cB];
    }
    __syncthreads();
    #pragma unroll
    for (int kk = 0; kk < 16; ++kk){
      float4 a = *(const float4*)&As[kk][ty*4];
      float4 b = *(const float4*)&Bs[kk][tx*4];
      acc[0][0] += a.x*b.x; acc[0][1] += a.x*b.y; acc[0][2] += a.x*b.z; acc[0][3] += a.x*b.w;
      acc[1][0] += a.y*b.x; acc[1][1] += a.y*b.y; acc[1][2] += a.y*b.z; acc[1][3] += a.y*b.w;
      acc[2][0] += a.z*b.x; acc[2][1] += a.z*b.y; acc[2][2] += a.z*b.z; acc[2][3] += a.z*b.w;
      acc[3][0] += a.w*b.x; acc[3][1] += a.w*b.y; acc[3][2] += a.w*b.z; acc[3][3] += a.w*b.w;
    }
    __syncthreads();
  }
  int o0 = n0 + tx*4;
  float b0 = bias[o0], b1v = bias[o0+1], b2v = bias[o0+2], b3 = bias[o0+3];
  #pragma unroll
  for (int i = 0; i < 4; ++i){
    int m = m0 + ty*4 + i;
    float4 r;
    r.x = fmaxf(acc[i][0] + b0,  0.f);
    r.y = fmaxf(acc[i][1] + b1v, 0.f);
    r.z = fmaxf(acc[i][2] + b2v, 0.f);
    r.w = fmaxf(acc[i][3] + b3,  0.f);
    *(float4*)&H[(size_t)m*256 + o0] = r;
  }
}

// ---------------- layer-2 GEMM + log_softmax: one wave per target row ----------------
__global__ void gemm2_logsoftmax(const float* __restrict__ agg2, const uint32_t* __restrict__ packedH,
                                 const float* __restrict__ Bcat2, const float* __restrict__ bias,
                                 float* __restrict__ out){
  int t = blockIdx.x;
  int lane = threadIdx.x;       // 64
  __shared__ float av[512];
  for (int k = lane; k < 256; k += 64) av[k] = agg2[(size_t)t*256 + k];
  const uint32_t* pr = packedH + (size_t)t*16;
  for (int k = lane; k < 256; k += 64){
    int w = k >> 5, b = k & 31;
    av[256 + k] = (float)((pr[w]>>b)&1) - (float)((pr[8+w]>>b)&1);
  }
  __syncthreads();
  bool active = lane < 41;
  float acc = active ? bias[lane] : 0.f;
  for (int k = 0; k < 512; ++k){
    float bw = active ? Bcat2[k*41 + lane] : 0.f;
    acc += av[k] * bw;
  }
  float v = active ? acc : -INFINITY;
  float m = v;
  #pragma unroll
  for (int off = 32; off; off >>= 1) m = fmaxf(m, __shfl_xor(m, off));
  float e = active ? expf(v - m) : 0.f;
  float ssum = e;
  #pragma unroll
  for (int off = 32; off; off >>= 1) ssum += __shfl_xor(ssum, off);
  if (active) out[(size_t)t*41 + lane] = v - m - logf(ssum);
}

extern "C" void kernel_launch(void* const* d_in, const int* in_sizes, int n_in,
                              void* d_out, int out_size, void* d_ws, size_t ws_size,
                              hipStream_t stream){
  (void)n_in; (void)out_size; (void)ws_size;
  const float* x   = (const float*)d_in[0];
  const int*   ei1 = (const int*)d_in[1];
  const int*   ei2 = (const int*)d_in[2];
  const float* W1l = (const float*)d_in[5];
  const float* W1r = (const float*)d_in[6];
  const float* b1  = (const float*)d_in[7];
  const float* W2l = (const float*)d_in[8];
  const float* W2r = (const float*)d_in[9];
  const float* b2  = (const float*)d_in[10];
  float* out = (float*)d_out;

  const int FIN = 602, N1 = 11264, NB = 1024;
  const int N0 = in_sizes[0] / FIN;
  const int E1 = in_sizes[1] / 2;
  const int E2 = in_sizes[2] / 2;

  char* wsb = (char*)d_ws;
  size_t off = 0;
  auto carve = [&](size_t bytes)->void*{
    void* p = wsb + off;
    off = (off + bytes + 255) & ~(size_t)255;
    return p;
  };
  uint32_t* packedX = (uint32_t*)carve((size_t)N0*40*4);   // 2-plane sign bits of norm_bin(x)
  uint32_t* packedH = (uint32_t*)carve((size_t)N1*16*4);   // 2-plane sign bits of norm_bin(h)
  float* agg1  = (float*)carve((size_t)N1*602*4);
  float* h     = (float*)carve((size_t)N1*256*4);
  float* agg2  = (float*)carve((size_t)NB*256*4);
  float* Bcat1 = (float*)carve((size_t)1216*256*4);
  float* Bcat2 = (float*)carve((size_t)512*41*4);
  float* aL  = (float*)carve(256*4);
  float* aR  = (float*)carve(256*4);
  float* a2L = (float*)carve(64*4);
  float* a2R = (float*)carve(64*4);
  int* deg1  = (int*)carve((size_t)N1*4);
  int* rs1   = (int*)carve((size_t)(N1+1)*4);
  int* cur1  = (int*)carve((size_t)N1*4);
  int* esrc1 = (int*)carve((size_t)E1*4);
  int* deg2  = (int*)carve((size_t)NB*4);
  int* rs2   = (int*)carve((size_t)(NB+1)*4);
  int* cur2  = (int*)carve((size_t)NB*4);
  int* esrc2 = (int*)carve((size_t)E2*4);

  // binarize weights
  row_absmean<<<256, 256, 0, stream>>>(W1l, aL, 602);
  row_absmean<<<256, 256, 0, stream>>>(W1r, aR, 602);
  row_absmean<<<41, 256, 0, stream>>>(W2l, a2L, 256);
  row_absmean<<<41, 256, 0, stream>>>(W2r, a2R, 256);
  fill_bcat1<<<CDIV(1216*256, 256), 256, 0, stream>>>(W1l, W1r, aL, aR, Bcat1);
  fill_bcat2<<<CDIV(512*41, 256), 256, 0, stream>>>(W2l, W2r, a2L, a2R, Bcat2);

  // norm_bin(x) -> packed signs (dominant HBM pass: 705 MB read)
  pack_sign_kernel<<<CDIV(N0, 4), 256, 0, stream>>>(x, packedX, N0, 602, 10, 20, 40);

  // CSR for edge_index1 (dst in [0, N1))
  zero_i32<<<CDIV(N1, 256), 256, 0, stream>>>(deg1, N1);
  count_deg<<<CDIV(E1, 256), 256, 0, stream>>>(ei1 + E1, E1, deg1);
  scan_kernel<<<1, 1024, 0, stream>>>(deg1, rs1, N1);
  copy_i32<<<CDIV(N1, 256), 256, 0, stream>>>(rs1, cur1, N1);
  fill_csr<<<CDIV(E1, 256), 256, 0, stream>>>(ei1, ei1 + E1, E1, cur1, esrc1);

  // segment-mean of signs (integer accumulation -> deterministic)
  aggregate_kernel<<<N1, 256, 0, stream>>>(packedX, 40, 20, 602, rs1, esrc1, agg1);

  // h = relu(agg1 @ B1l^T + sgn(x_t) @ B1r^T + b1)
  gemm1_kernel<<<dim3(4, 176), 256, 0, stream>>>(agg1, packedX, Bcat1, b1, h);

  // norm_bin(h) -> packed signs
  pack_sign_kernel<<<CDIV(N1, 4), 256, 0, stream>>>(h, packedH, N1, 256, 4, 8, 16);

  // CSR for edge_index2 (dst in [0, NB))
  zero_i32<<<CDIV(NB, 256), 256, 0, stream>>>(deg2, NB);
  count_deg<<<CDIV(E2, 256), 256, 0, stream>>>(ei2 + E2, E2, deg2);
  scan_kernel<<<1, 1024, 0, stream>>>(deg2, rs2, NB);
  copy_i32<<<CDIV(NB, 256), 256, 0, stream>>>(rs2, cur2, NB);
  fill_csr<<<CDIV(E2, 256), 256, 0, stream>>>(ei2, ei2 + E2, E2, cur2, esrc2);

  aggregate_kernel<<<NB, 256, 0, stream>>>(packedH, 16, 8, 256, rs2, esrc2, agg2);

  // out = log_softmax(agg2 @ B2l^T + sgn(h_t) @ B2r^T + b2)
  gemm2_logsoftmax<<<NB, 64, 0, stream>>>(agg2, packedH, Bcat2, b2, out);
}

// Round 2
// 555.584 us; speedup vs baseline: 1.5086x; 1.5086x over previous
//
#include <hip/hip_runtime.h>
#include <cstdint>
#include <cstddef>

#define CDIV(a,b) (((a)+(b)-1)/(b))

__device__ __forceinline__ float sgnf(float w){ return (w>0.f)?1.f:((w<0.f)?-1.f:0.f); }

// ---------------- weight binarization ----------------
__global__ void row_absmean(const float* __restrict__ W, float* __restrict__ alpha, int K){
  int r = blockIdx.x;
  const float* wr = W + (size_t)r*K;
  float s = 0.f;
  for (int k = threadIdx.x; k < K; k += blockDim.x) s += fabsf(wr[k]);
  #pragma unroll
  for (int off = 32; off; off >>= 1) s += __shfl_xor(s, off);
  __shared__ float red[8];
  int wid = threadIdx.x >> 6, lane = threadIdx.x & 63;
  if (lane == 0) red[wid] = s;
  __syncthreads();
  if (threadIdx.x == 0){
    float t = 0.f; int nw = blockDim.x >> 6;
    for (int i = 0; i < nw; ++i) t += red[i];
    alpha[r] = t / (float)K;
  }
}

// Bcat1: [1216][256], rows 0..601 = aL[o]*sign(W1l[o][k]); 602..1203 = aR[o]*sign(W1r[o][k-602]); 1204..1215 = 0
__global__ void fill_bcat1(const float* __restrict__ Wl, const float* __restrict__ Wr,
                           const float* __restrict__ aL, const float* __restrict__ aR,
                           float* __restrict__ Bcat){
  int idx = blockIdx.x*blockDim.x + threadIdx.x;
  if (idx >= 1216*256) return;
  int o = idx & 255, k = idx >> 8;
  float v = 0.f;
  if (k < 602)       v = aL[o] * sgnf(Wl[(size_t)o*602 + k]);
  else if (k < 1204) v = aR[o] * sgnf(Wr[(size_t)o*602 + (k-602)]);
  Bcat[idx] = v;
}

// Bcat2: [512][41]
__global__ void fill_bcat2(const float* __restrict__ Wl, const float* __restrict__ Wr,
                           const float* __restrict__ aL, const float* __restrict__ aR,
                           float* __restrict__ Bcat){
  int idx = blockIdx.x*blockDim.x + threadIdx.x;
  if (idx >= 512*41) return;
  int o = idx % 41, k = idx / 41;
  float v;
  if (k < 256) v = aL[o] * sgnf(Wl[(size_t)o*256 + k]);
  else         v = aR[o] * sgnf(Wr[(size_t)o*256 + (k-256)]);
  Bcat[idx] = v;
}

// ---------------- sign-pack v2: single pass, row held in registers ----------------
// Layout per row: [pos words 0..WPP-1][neg words 0..WPP-1]; bit b of word w = column 32w+b.
// NG = number of 64-col ballot groups; WPP = padded words per plane (2*NG).
template<int NCOLS, int NG, int WPP>
__global__ void pack_v2(const float* __restrict__ X, uint32_t* __restrict__ P, int nrows){
  const int wpb = blockDim.x >> 6;
  const int row = blockIdx.x * wpb + (threadIdx.x >> 6);
  const int lane = threadIdx.x & 63;
  if (row >= nrows) return;
  const float* xr = X + (size_t)row * NCOLS;
  float v[NG];
  float s = 0.f;
  #pragma unroll
  for (int g = 0; g < NG; ++g){
    int c = g*64 + lane;
    if (c < NCOLS){ v[g] = xr[c]; s += v[g]; } else v[g] = 0.f;
  }
  #pragma unroll
  for (int off = 32; off; off >>= 1) s += __shfl_xor(s, off);
  const float mean = s / (float)NCOLS;
  uint32_t wpos[WPP], wneg[WPP];
  #pragma unroll
  for (int g = 0; g < NG; ++g){
    int c = g*64 + lane;
    bool valid = c < NCOLS;
    float d = v[g] - mean;
    unsigned long long bp = __ballot(valid && (d > 0.f));
    unsigned long long bn = __ballot(valid && (d < 0.f));
    wpos[2*g]   = (uint32_t)bp;  wpos[2*g+1] = (uint32_t)(bp >> 32);
    wneg[2*g]   = (uint32_t)bn;  wneg[2*g+1] = (uint32_t)(bn >> 32);
  }
  if (lane == 0){
    uint32_t* pr = P + (size_t)row * (2*WPP);
    #pragma unroll
    for (int q = 0; q < WPP/4; ++q){
      uint4 a; a.x = wpos[4*q]; a.y = wpos[4*q+1]; a.z = wpos[4*q+2]; a.w = wpos[4*q+3];
      *(uint4*)&pr[4*q] = a;
      uint4 b; b.x = wneg[4*q]; b.y = wneg[4*q+1]; b.z = wneg[4*q+2]; b.w = wneg[4*q+3];
      *(uint4*)&pr[WPP + 4*q] = b;
    }
  }
}

// ---------------- CSR build ----------------
__global__ void zero_i32(int* __restrict__ p, int n){
  int i = blockIdx.x*blockDim.x + threadIdx.x;
  if (i < n) p[i] = 0;
}
__global__ void copy_i32(const int* __restrict__ a, int* __restrict__ b, int n){
  int i = blockIdx.x*blockDim.x + threadIdx.x;
  if (i < n) b[i] = a[i];
}
__global__ void count_deg(const int* __restrict__ dst, int E, int* __restrict__ deg){
  int e = blockIdx.x*blockDim.x + threadIdx.x;
  if (e < E) atomicAdd(&deg[dst[e]], 1);
}
__global__ void scan_kernel(const int* __restrict__ deg, int* __restrict__ rs, int n){
  __shared__ int partial[1024];
  int tid = threadIdx.x;
  int per = CDIV(n, 1024);
  int begin = tid*per; if (begin > n) begin = n;
  int end = begin + per; if (end > n) end = n;
  int s = 0;
  for (int i = begin; i < end; ++i) s += deg[i];
  partial[tid] = s;
  __syncthreads();
  for (int off = 1; off < 1024; off <<= 1){
    int add = (tid >= off) ? partial[tid-off] : 0;
    __syncthreads();
    partial[tid] += add;
    __syncthreads();
  }
  int prefix = (tid == 0) ? 0 : partial[tid-1];
  for (int i = begin; i < end; ++i){ rs[i] = prefix; prefix += deg[i]; }
  if (tid == 1023) rs[n] = prefix;
}
__global__ void fill_csr(const int* __restrict__ src, const int* __restrict__ dst, int E,
                         int* __restrict__ cur, int* __restrict__ esrc){
  int e = blockIdx.x*blockDim.x + threadIdx.x;
  if (e < E){
    int p = atomicAdd(&cur[dst[e]], 1);
    esrc[p] = src[e];
  }
}

// ---------------- aggregate v2: byte-SIMD per-word accumulation, 1 wave/target ----------------
// Lane w (< WUSED) owns word w of both planes: 8 byte-packed accumulators each for pos/neg.
// Byte k of p[b] counts column 32w + b + 8k.  deg <= ~60 << 255, no overflow.
template<int WUSED, int HALF, int STRIDE, int NCOLS>
__global__ void aggregate_v2(const uint32_t* __restrict__ packed,
                             const int* __restrict__ rs, const int* __restrict__ esrc,
                             float* __restrict__ agg){
  const int t = blockIdx.x;
  const int lane = threadIdx.x;     // 64
  const int s0 = rs[t], s1 = rs[t+1];
  uint32_t p[8] = {0,0,0,0,0,0,0,0};
  uint32_t n[8] = {0,0,0,0,0,0,0,0};
  if (lane < WUSED){
    for (int e = s0; e < s1; ++e){
      int src = esrc[e];
      const uint32_t* pr = packed + (size_t)src * STRIDE;
      uint32_t wp = pr[lane];
      uint32_t wn = pr[HALF + lane];
      #pragma unroll
      for (int b = 0; b < 8; ++b){
        p[b] += (wp >> b) & 0x01010101u;
        n[b] += (wn >> b) & 0x01010101u;
      }
    }
  }
  int deg = s1 - s0;
  float inv = 1.f / (float)(deg > 0 ? deg : 1);
  if (lane < WUSED){
    float* ar = agg + (size_t)t * NCOLS;
    #pragma unroll
    for (int b = 0; b < 8; ++b){
      #pragma unroll
      for (int k = 0; k < 4; ++k){
        int col = 32*lane + b + 8*k;
        if (col < NCOLS){
          int cnt = (int)((p[b] >> (8*k)) & 0xFF) - (int)((n[b] >> (8*k)) & 0xFF);
          ar[col] = (float)cnt * inv;
        }
      }
    }
  }
}

// ---------------- layer-1 GEMM: H = relu([agg1 | sgn_xt] @ Bcat1 + b1) ----------------
// M=11264, N=256, K=1216. 128x64 tile, K-chunk 16, 8x4 acc/thread, 256 threads, grid (4,88).
__global__ __launch_bounds__(256) void gemm1_v3(
    const float* __restrict__ agg1, const uint32_t* __restrict__ packedX,
    const float* __restrict__ Bcat, const float* __restrict__ bias,
    float* __restrict__ H){
  __shared__ __align__(16) float As[16][128];
  __shared__ __align__(16) float Bs[16][64];
  const int tid = threadIdx.x;
  const int m0 = blockIdx.y * 128, n0 = blockIdx.x * 64;
  const int tx = tid & 15, ty = tid >> 4;
  const int arow = tid & 127, k8 = (tid >> 7) * 8;
  const int bk = tid >> 4, bc4 = (tid & 15) * 4;
  const float* aggRow = agg1 + (size_t)(m0 + arow) * 602;
  const uint32_t* prRow = packedX + (size_t)(m0 + arow) * 40;
  float acc[8][4] = {};
  for (int k0 = 0; k0 < 1216; k0 += 16){
    // ---- stage A (128 rows x 16 k), 8 elems/thread ----
    if (k0 + 16 <= 602){
      // pure agg: float2 loads (agg row base is 8B-aligned)
      #pragma unroll
      for (int i = 0; i < 4; ++i){
        float2 v = *(const float2*)&aggRow[k0 + k8 + 2*i];
        As[k8 + 2*i    ][arow] = v.x;
        As[k8 + 2*i + 1][arow] = v.y;
      }
    } else if (k0 >= 608){
      // pure bits (pad cols >= 602 read zero bits by construction)
      #pragma unroll
      for (int j = 0; j < 8; ++j){
        int f = k0 + k8 + j - 602;
        int w = f >> 5, b = f & 31;
        As[k8 + j][arow] = (float)((prRow[w] >> b) & 1) - (float)((prRow[20 + w] >> b) & 1);
      }
    } else {
      // single straddling chunk (k0 = 592)
      #pragma unroll
      for (int j = 0; j < 8; ++j){
        int kg = k0 + k8 + j;
        float v;
        if (kg < 602) v = aggRow[kg];
        else {
          int f = kg - 602; int w = f >> 5, b = f & 31;
          v = (float)((prRow[w] >> b) & 1) - (float)((prRow[20 + w] >> b) & 1);
        }
        As[k8 + j][arow] = v;
      }
    }
    // ---- stage B (16 k x 64 cols), float4 ----
    {
      float4 v = *(const float4*)&Bcat[(size_t)(k0 + bk)*256 + n0 + bc4];
      *(float4*)&Bs[bk][bc4] = v;
    }
    __syncthreads();
    #pragma unroll
    for (int kk = 0; kk < 16; ++kk){
      float4 a0 = *(const float4*)&As[kk][ty*8];
      float4 a1 = *(const float4*)&As[kk][ty*8 + 4];
      float4 b  = *(const float4*)&Bs[kk][tx*4];
      acc[0][0] += a0.x*b.x; acc[0][1] += a0.x*b.y; acc[0][2] += a0.x*b.z; acc[0][3] += a0.x*b.w;
      acc[1][0] += a0.y*b.x; acc[1][1] += a0.y*b.y; acc[1][2] += a0.y*b.z; acc[1][3] += a0.y*b.w;
      acc[2][0] += a0.z*b.x; acc[2][1] += a0.z*b.y; acc[2][2] += a0.z*b.z; acc[2][3] += a0.z*b.w;
      acc[3][0] += a0.w*b.x; acc[3][1] += a0.w*b.y; acc[3][2] += a0.w*b.z; acc[3][3] += a0.w*b.w;
      acc[4][0] += a1.x*b.x; acc[4][1] += a1.x*b.y; acc[4][2] += a1.x*b.z; acc[4][3] += a1.x*b.w;
      acc[5][0] += a1.y*b.x; acc[5][1] += a1.y*b.y; acc[5][2] += a1.y*b.z; acc[5][3] += a1.y*b.w;
      acc[6][0] += a1.z*b.x; acc[6][1] += a1.z*b.y; acc[6][2] += a1.z*b.z; acc[6][3] += a1.z*b.w;
      acc[7][0] += a1.w*b.x; acc[7][1] += a1.w*b.y; acc[7][2] += a1.w*b.z; acc[7][3] += a1.w*b.w;
    }
    __syncthreads();
  }
  const int o0 = n0 + tx*4;
  const float4 bb = *(const float4*)&bias[o0];
  #pragma unroll
  for (int i = 0; i < 8; ++i){
    int m = m0 + ty*8 + i;
    float4 r;
    r.x = fmaxf(acc[i][0] + bb.x, 0.f);
    r.y = fmaxf(acc[i][1] + bb.y, 0.f);
    r.z = fmaxf(acc[i][2] + bb.z, 0.f);
    r.w = fmaxf(acc[i][3] + bb.w, 0.f);
    *(float4*)&H[(size_t)m*256 + o0] = r;
  }
}

// ---------------- layer-2 GEMM + log_softmax: one wave per target row ----------------
__global__ void gemm2_logsoftmax(const float* __restrict__ agg2, const uint32_t* __restrict__ packedH,
                                 const float* __restrict__ Bcat2, const float* __restrict__ bias,
                                 float* __restrict__ out){
  int t = blockIdx.x;
  int lane = threadIdx.x;       // 64
  __shared__ float av[512];
  for (int k = lane; k < 256; k += 64) av[k] = agg2[(size_t)t*256 + k];
  const uint32_t* pr = packedH + (size_t)t*16;
  for (int k = lane; k < 256; k += 64){
    int w = k >> 5, b = k & 31;
    av[256 + k] = (float)((pr[w]>>b)&1) - (float)((pr[8+w]>>b)&1);
  }
  __syncthreads();
  bool active = lane < 41;
  float acc = active ? bias[lane] : 0.f;
  for (int k = 0; k < 512; ++k){
    float bw = active ? Bcat2[k*41 + lane] : 0.f;
    acc += av[k] * bw;
  }
  float v = active ? acc : -INFINITY;
  float m = v;
  #pragma unroll
  for (int off = 32; off; off >>= 1) m = fmaxf(m, __shfl_xor(m, off));
  float e = active ? expf(v - m) : 0.f;
  float ssum = e;
  #pragma unroll
  for (int off = 32; off; off >>= 1) ssum += __shfl_xor(ssum, off);
  if (active) out[(size_t)t*41 + lane] = v - m - logf(ssum);
}

extern "C" void kernel_launch(void* const* d_in, const int* in_sizes, int n_in,
                              void* d_out, int out_size, void* d_ws, size_t ws_size,
                              hipStream_t stream){
  (void)n_in; (void)out_size; (void)ws_size;
  const float* x   = (const float*)d_in[0];
  const int*   ei1 = (const int*)d_in[1];
  const int*   ei2 = (const int*)d_in[2];
  const float* W1l = (const float*)d_in[5];
  const float* W1r = (const float*)d_in[6];
  const float* b1  = (const float*)d_in[7];
  const float* W2l = (const float*)d_in[8];
  const float* W2r = (const float*)d_in[9];
  const float* b2  = (const float*)d_in[10];
  float* out = (float*)d_out;

  const int FIN = 602, N1 = 11264, NB = 1024;
  const int N0 = in_sizes[0] / FIN;
  const int E1 = in_sizes[1] / 2;
  const int E2 = in_sizes[2] / 2;

  char* wsb = (char*)d_ws;
  size_t off = 0;
  auto carve = [&](size_t bytes)->void*{
    void* p = wsb + off;
    off = (off + bytes + 255) & ~(size_t)255;
    return p;
  };
  uint32_t* packedX = (uint32_t*)carve((size_t)N0*40*4);
  uint32_t* packedH = (uint32_t*)carve((size_t)N1*16*4);
  float* agg1  = (float*)carve((size_t)N1*602*4);
  float* h     = (float*)carve((size_t)N1*256*4);
  float* agg2  = (float*)carve((size_t)NB*256*4);
  float* Bcat1 = (float*)carve((size_t)1216*256*4);
  float* Bcat2 = (float*)carve((size_t)512*41*4);
  float* aL  = (float*)carve(256*4);
  float* aR  = (float*)carve(256*4);
  float* a2L = (float*)carve(64*4);
  float* a2R = (float*)carve(64*4);
  int* deg1  = (int*)carve((size_t)N1*4);
  int* rs1   = (int*)carve((size_t)(N1+1)*4);
  int* cur1  = (int*)carve((size_t)N1*4);
  int* esrc1 = (int*)carve((size_t)E1*4);
  int* deg2  = (int*)carve((size_t)NB*4);
  int* rs2   = (int*)carve((size_t)(NB+1)*4);
  int* cur2  = (int*)carve((size_t)NB*4);
  int* esrc2 = (int*)carve((size_t)E2*4);

  // binarize weights
  row_absmean<<<256, 256, 0, stream>>>(W1l, aL, 602);
  row_absmean<<<256, 256, 0, stream>>>(W1r, aR, 602);
  row_absmean<<<41, 256, 0, stream>>>(W2l, a2L, 256);
  row_absmean<<<41, 256, 0, stream>>>(W2r, a2R, 256);
  fill_bcat1<<<CDIV(1216*256, 256), 256, 0, stream>>>(W1l, W1r, aL, aR, Bcat1);
  fill_bcat2<<<CDIV(512*41, 256), 256, 0, stream>>>(W2l, W2r, a2L, a2R, Bcat2);

  // norm_bin(x) -> packed signs, single pass
  pack_v2<602,10,20><<<CDIV(N0, 4), 256, 0, stream>>>(x, packedX, N0);

  // CSR for edge_index1
  zero_i32<<<CDIV(N1, 256), 256, 0, stream>>>(deg1, N1);
  count_deg<<<CDIV(E1, 256), 256, 0, stream>>>(ei1 + E1, E1, deg1);
  scan_kernel<<<1, 1024, 0, stream>>>(deg1, rs1, N1);
  copy_i32<<<CDIV(N1, 256), 256, 0, stream>>>(rs1, cur1, N1);
  fill_csr<<<CDIV(E1, 256), 256, 0, stream>>>(ei1, ei1 + E1, E1, cur1, esrc1);

  // segment-mean of signs (byte-SIMD, deterministic)
  aggregate_v2<19,20,40,602><<<N1, 64, 0, stream>>>(packedX, rs1, esrc1, agg1);

  // h = relu(agg1 @ B1l^T + sgn(x_t) @ B1r^T + b1)
  gemm1_v3<<<dim3(4, 88), 256, 0, stream>>>(agg1, packedX, Bcat1, b1, h);

  // norm_bin(h) -> packed signs
  pack_v2<256,4,8><<<CDIV(N1, 4), 256, 0, stream>>>(h, packedH, N1);

  // CSR for edge_index2
  zero_i32<<<CDIV(NB, 256), 256, 0, stream>>>(deg2, NB);
  count_deg<<<CDIV(E2, 256), 256, 0, stream>>>(ei2 + E2, E2, deg2);
  scan_kernel<<<1, 1024, 0, stream>>>(deg2, rs2, NB);
  copy_i32<<<CDIV(NB, 256), 256, 0, stream>>>(rs2, cur2, NB);
  fill_csr<<<CDIV(E2, 256), 256, 0, stream>>>(ei2, ei2 + E2, E2, cur2, esrc2);

  aggregate_v2<8,8,16,256><<<NB, 64, 0, stream>>>(packedH, rs2, esrc2, agg2);

  // out = log_softmax(agg2 @ B2l^T + sgn(h_t) @ B2r^T + b2)
  gemm2_logsoftmax<<<NB, 64, 0, stream>>>(agg2, packedH, Bcat2, b2, out);
}

// Round 3
// 340.350 us; speedup vs baseline: 2.4626x; 1.6324x over previous
//
#include <hip/hip_runtime.h>
#include <hip/hip_bf16.h>
#include <cstdint>
#include <cstddef>

#define CDIV(a,b) (((a)+(b)-1)/(b))

using bf16x8 = __attribute__((ext_vector_type(8))) short;
using f32x4  = __attribute__((ext_vector_type(4))) float;

__device__ __forceinline__ unsigned short sgn_bf16(float s){
  return (s > 0.f) ? 0x3F80u : ((s < 0.f) ? 0xBF80u : 0u);
}

// ---------------- alphas: all 4 weight matrices in one launch ----------------
// blocks 0..255 -> W1l rows (K=602); 256..511 -> W1r; 512..552 -> W2l (K=256); 553..593 -> W2r
__global__ void prep_alpha(const float* __restrict__ W1l, const float* __restrict__ W1r,
                           const float* __restrict__ W2l, const float* __restrict__ W2r,
                           float* __restrict__ aL, float* __restrict__ aR,
                           float* __restrict__ a2L, float* __restrict__ a2R){
  int r = blockIdx.x;
  const float* wr; float* dst; int K;
  if (r < 256){ wr = W1l + (size_t)r*602; dst = aL + r; K = 602; }
  else if (r < 512){ int q = r-256; wr = W1r + (size_t)q*602; dst = aR + q; K = 602; }
  else if (r < 553){ int q = r-512; wr = W2l + (size_t)q*256; dst = a2L + q; K = 256; }
  else { int q = r-553; wr = W2r + (size_t)q*256; dst = a2R + q; K = 256; }
  float s = 0.f;
  for (int k = threadIdx.x; k < K; k += blockDim.x) s += fabsf(wr[k]);
  #pragma unroll
  for (int off = 32; off; off >>= 1) s += __shfl_xor(s, off);
  __shared__ float red[4];
  int wid = threadIdx.x >> 6, lane = threadIdx.x & 63;
  if (lane == 0) red[wid] = s;
  __syncthreads();
  if (threadIdx.x == 0){
    float t = red[0] + red[1] + red[2] + red[3];
    *dst = t / (float)K;
  }
}

// bsgn: [256 cols][1216 k] bf16 bits. k<602: sgn(W1l[o][k]); 602..607: 0;
// 608..1209: sgn(W1r[o][k-608]); 1210..1215: 0.
__global__ void fill_bsgn(const float* __restrict__ W1l, const float* __restrict__ W1r,
                          unsigned short* __restrict__ bsgn){
  int idx = blockIdx.x*blockDim.x + threadIdx.x;
  if (idx >= 256*1216) return;
  int o = idx / 1216, k = idx - o*1216;
  float v = 0.f;
  if (k < 602) v = W1l[(size_t)o*602 + k];
  else if (k >= 608 && k < 1210) v = W1r[(size_t)o*602 + (k-608)];
  bsgn[idx] = sgn_bf16(v);
}

// Bcat2: [512][41] f32, k-major (layer 2 stays on VALU — 43 MFLOP)
__global__ void fill_bcat2(const float* __restrict__ Wl, const float* __restrict__ Wr,
                           const float* __restrict__ aL, const float* __restrict__ aR,
                           float* __restrict__ Bcat){
  int idx = blockIdx.x*blockDim.x + threadIdx.x;
  if (idx >= 512*41) return;
  int o = idx % 41, k = idx / 41;
  float w = (k < 256) ? Wl[(size_t)o*256 + k] : Wr[(size_t)o*256 + (k-256)];
  float a = (k < 256) ? aL[o] : aR[o];
  float sg = (w > 0.f) ? 1.f : ((w < 0.f) ? -1.f : 0.f);
  Bcat[idx] = a * sg;
}

// ---------------- sign-pack: single pass, row in registers ----------------
template<int NCOLS, int NG, int WPP>
__global__ void pack_v2(const float* __restrict__ X, uint32_t* __restrict__ P, int nrows){
  const int wpb = blockDim.x >> 6;
  const int row = blockIdx.x * wpb + (threadIdx.x >> 6);
  const int lane = threadIdx.x & 63;
  if (row >= nrows) return;
  const float* xr = X + (size_t)row * NCOLS;
  float v[NG];
  float s = 0.f;
  #pragma unroll
  for (int g = 0; g < NG; ++g){
    int c = g*64 + lane;
    if (c < NCOLS){ v[g] = xr[c]; s += v[g]; } else v[g] = 0.f;
  }
  #pragma unroll
  for (int off = 32; off; off >>= 1) s += __shfl_xor(s, off);
  const float mean = s / (float)NCOLS;
  uint32_t wpos[WPP], wneg[WPP];
  #pragma unroll
  for (int g = 0; g < NG; ++g){
    int c = g*64 + lane;
    bool valid = c < NCOLS;
    float d = v[g] - mean;
    unsigned long long bp = __ballot(valid && (d > 0.f));
    unsigned long long bn = __ballot(valid && (d < 0.f));
    wpos[2*g]   = (uint32_t)bp;  wpos[2*g+1] = (uint32_t)(bp >> 32);
    wneg[2*g]   = (uint32_t)bn;  wneg[2*g+1] = (uint32_t)(bn >> 32);
  }
  if (lane == 0){
    uint32_t* pr = P + (size_t)row * (2*WPP);
    #pragma unroll
    for (int q = 0; q < WPP/4; ++q){
      uint4 a; a.x = wpos[4*q]; a.y = wpos[4*q+1]; a.z = wpos[4*q+2]; a.w = wpos[4*q+3];
      *(uint4*)&pr[4*q] = a;
      uint4 b; b.x = wneg[4*q]; b.y = wneg[4*q+1]; b.z = wneg[4*q+2]; b.w = wneg[4*q+3];
      *(uint4*)&pr[WPP + 4*q] = b;
    }
  }
}

// ---------------- CSR build (both edge sets, merged launches) ----------------
__global__ void zero_i32(int* __restrict__ p, int n){
  int i = blockIdx.x*blockDim.x + threadIdx.x;
  if (i < n) p[i] = 0;
}
__global__ void count_both(const int* __restrict__ d1, int E1, int* __restrict__ deg1,
                           const int* __restrict__ d2, int E2, int* __restrict__ deg2){
  int e = blockIdx.x*blockDim.x + threadIdx.x;
  if (e < E1) atomicAdd(&deg1[d1[e]], 1);
  else if (e < E1 + E2) atomicAdd(&deg2[d2[e - E1]], 1);
}
// block 0 scans deg1 (n1), block 1 scans deg2 (n2); also writes cur[] = rs[]
__global__ void scan2_kernel(const int* __restrict__ deg1, int* __restrict__ rs1, int* __restrict__ cur1, int n1,
                             const int* __restrict__ deg2, int* __restrict__ rs2, int* __restrict__ cur2, int n2){
  const int* deg = blockIdx.x ? deg2 : deg1;
  int* rs  = blockIdx.x ? rs2  : rs1;
  int* cur = blockIdx.x ? cur2 : cur1;
  int n    = blockIdx.x ? n2   : n1;
  __shared__ int partial[1024];
  int tid = threadIdx.x;
  int per = CDIV(n, 1024);
  int begin = tid*per; if (begin > n) begin = n;
  int end = begin + per; if (end > n) end = n;
  int s = 0;
  for (int i = begin; i < end; ++i) s += deg[i];
  partial[tid] = s;
  __syncthreads();
  for (int off = 1; off < 1024; off <<= 1){
    int add = (tid >= off) ? partial[tid-off] : 0;
    __syncthreads();
    partial[tid] += add;
    __syncthreads();
  }
  int prefix = (tid == 0) ? 0 : partial[tid-1];
  for (int i = begin; i < end; ++i){ rs[i] = prefix; cur[i] = prefix; prefix += deg[i]; }
  if (tid == 1023) rs[n] = prefix;
}
__global__ void fill_both(const int* __restrict__ s1, const int* __restrict__ d1, int E1,
                          int* __restrict__ cur1, int* __restrict__ esrc1,
                          const int* __restrict__ s2, const int* __restrict__ d2, int E2,
                          int* __restrict__ cur2, int* __restrict__ esrc2){
  int e = blockIdx.x*blockDim.x + threadIdx.x;
  if (e < E1){
    int p = atomicAdd(&cur1[d1[e]], 1);
    esrc1[p] = s1[e];
  } else if (e < E1 + E2){
    int q = e - E1;
    int p = atomicAdd(&cur2[d2[q]], 1);
    esrc2[p] = s2[q];
  }
}

// ---------------- aggregate (layer 1): byte-SIMD -> bf16 S + invdeg ----------------
// Lane w < WUSED owns word w of both planes; byte k of p[b] counts column 32w+b+8k.
// Emits S (integer, exact in bf16) and invdeg; pad cols have zero bits -> S=0.
template<int WUSED, int HALF, int STRIDE, int KPAD>
__global__ void aggregate_bf16(const uint32_t* __restrict__ packed,
                               const int* __restrict__ rs, const int* __restrict__ esrc,
                               unsigned short* __restrict__ S, float* __restrict__ invdeg){
  const int t = blockIdx.x;
  const int lane = threadIdx.x;     // 64
  const int s0 = rs[t], s1 = rs[t+1];
  uint32_t p[8] = {0,0,0,0,0,0,0,0};
  uint32_t n[8] = {0,0,0,0,0,0,0,0};
  if (lane < WUSED){
    for (int e = s0; e < s1; ++e){
      const uint32_t* pr = packed + (size_t)esrc[e] * STRIDE;
      uint32_t wp = pr[lane];
      uint32_t wn = pr[HALF + lane];
      #pragma unroll
      for (int b = 0; b < 8; ++b){
        p[b] += (wp >> b) & 0x01010101u;
        n[b] += (wn >> b) & 0x01010101u;
      }
    }
  }
  if (lane == 0){
    int deg = s1 - s0;
    invdeg[t] = 1.f / (float)(deg > 0 ? deg : 1);
  }
  if (lane < WUSED){
    unsigned short* sr = S + (size_t)t * KPAD;
    #pragma unroll
    for (int b = 0; b < 8; ++b){
      #pragma unroll
      for (int k = 0; k < 4; ++k){
        int col = 32*lane + b + 8*k;
        int cnt = (int)((p[b] >> (8*k)) & 0xFF) - (int)((n[b] >> (8*k)) & 0xFF);
        float f = (float)cnt;                     // |cnt| <= deg << 256 -> bf16-exact
        sr[col] = (unsigned short)(__float_as_uint(f) >> 16);
      }
    }
  }
}

// ---------------- aggregate (layer 2): f32 mean, as before ----------------
template<int WUSED, int HALF, int STRIDE, int NCOLS>
__global__ void aggregate_f32(const uint32_t* __restrict__ packed,
                              const int* __restrict__ rs, const int* __restrict__ esrc,
                              float* __restrict__ agg){
  const int t = blockIdx.x;
  const int lane = threadIdx.x;
  const int s0 = rs[t], s1 = rs[t+1];
  uint32_t p[8] = {0,0,0,0,0,0,0,0};
  uint32_t n[8] = {0,0,0,0,0,0,0,0};
  if (lane < WUSED){
    for (int e = s0; e < s1; ++e){
      const uint32_t* pr = packed + (size_t)esrc[e] * STRIDE;
      uint32_t wp = pr[lane];
      uint32_t wn = pr[HALF + lane];
      #pragma unroll
      for (int b = 0; b < 8; ++b){
        p[b] += (wp >> b) & 0x01010101u;
        n[b] += (wn >> b) & 0x01010101u;
      }
    }
  }
  int deg = s1 - s0;
  float inv = 1.f / (float)(deg > 0 ? deg : 1);
  if (lane < WUSED){
    float* ar = agg + (size_t)t * NCOLS;
    #pragma unroll
    for (int b = 0; b < 8; ++b){
      #pragma unroll
      for (int k = 0; k < 4; ++k){
        int col = 32*lane + b + 8*k;
        int cnt = (int)((p[b] >> (8*k)) & 0xFF) - (int)((n[b] >> (8*k)) & 0xFF);
        ar[col] = (float)cnt * inv;
      }
    }
  }
}

// ---------------- layer-1 MFMA GEMM ----------------
// H[m][o] = relu(invdeg[m]*aL[o]*(S@sgnWl^T)[m][o] + aR[o]*(sgnX@sgnWr^T)[m][o] + b[o])
// A seg1 = S bf16 [M][608]; A seg2 = sign bits from packedX (608 bits). B = bsgn [256][1216].
// Block: 256 thr (4 waves, 2Mx2N), tile 64x128; wave-tile 32x64; mfma 16x16x32 bf16.
__global__ __launch_bounds__(256) void gemm1_mfma(
    const unsigned short* __restrict__ Sx, const uint32_t* __restrict__ packedX,
    const unsigned short* __restrict__ bsgn, const float* __restrict__ invdeg,
    const float* __restrict__ aL, const float* __restrict__ aR,
    const float* __restrict__ bias, float* __restrict__ H){
  __shared__ __align__(16) unsigned short As[64][40];   // 32 k + 8 pad (bank spread)
  __shared__ __align__(16) unsigned short Bs[128][40];
  const int tid = threadIdx.x;
  const int lane = tid & 63, wid = tid >> 6;
  const int wm = wid & 1, wn = wid >> 1;
  const int m0 = blockIdx.y * 64, n0 = blockIdx.x * 128;
  const int sArow = tid >> 2, sAk = (tid & 3) * 8;      // A: 64 rows x 32k, 8/thread
  const int sBcol = tid >> 1, sBk = (tid & 1) * 16;     // B: 128 cols x 32k, 16/thread
  const int frow = lane & 15, fk = (lane >> 4) * 8;
  f32x4 acc1[2][4], acc2[2][4];
  #pragma unroll
  for (int i = 0; i < 2; ++i)
    #pragma unroll
    for (int j = 0; j < 4; ++j){ f32x4 z = {0.f,0.f,0.f,0.f}; acc1[i][j] = z; acc2[i][j] = z; }

  const unsigned short* SxRow = Sx + (size_t)(m0 + sArow) * 608;
  const uint32_t* pxRow = packedX + (size_t)(m0 + sArow) * 40;
  const unsigned short* bsgnRow = bsgn + (size_t)(n0 + sBcol) * 1216;

  // ----- segment 1: k in [0,608), A = S -----
  for (int kc = 0; kc < 608; kc += 32){
    *(bf16x8*)&As[sArow][sAk] = *(const bf16x8*)&SxRow[kc + sAk];
    *(bf16x8*)&Bs[sBcol][sBk]     = *(const bf16x8*)&bsgnRow[kc + sBk];
    *(bf16x8*)&Bs[sBcol][sBk + 8] = *(const bf16x8*)&bsgnRow[kc + sBk + 8];
    __syncthreads();
    bf16x8 a0 = *(bf16x8*)&As[wm*32 + frow][fk];
    bf16x8 a1 = *(bf16x8*)&As[wm*32 + 16 + frow][fk];
    #pragma unroll
    for (int nf = 0; nf < 4; ++nf){
      bf16x8 b = *(bf16x8*)&Bs[wn*64 + nf*16 + frow][fk];
      acc1[0][nf] = __builtin_amdgcn_mfma_f32_16x16x32_bf16(a0, b, acc1[0][nf], 0, 0, 0);
      acc1[1][nf] = __builtin_amdgcn_mfma_f32_16x16x32_bf16(a1, b, acc1[1][nf], 0, 0, 0);
    }
    __syncthreads();
  }
  // ----- segment 2: k in [608,1216), A = unpacked sign bits -----
  for (int kc = 0; kc < 608; kc += 32){
    int w = kc >> 5;
    {
      uint32_t wp = pxRow[w];
      uint32_t wq = pxRow[20 + w];
      unsigned short tmp[8];
      #pragma unroll
      for (int j = 0; j < 8; ++j){
        int b_ = sAk + j;
        tmp[j] = ((wp >> b_) & 1) ? 0x3F80u : (((wq >> b_) & 1) ? 0xBF80u : 0u);
      }
      *(bf16x8*)&As[sArow][sAk] = *(bf16x8*)tmp;
    }
    *(bf16x8*)&Bs[sBcol][sBk]     = *(const bf16x8*)&bsgnRow[608 + kc + sBk];
    *(bf16x8*)&Bs[sBcol][sBk + 8] = *(const bf16x8*)&bsgnRow[608 + kc + sBk + 8];
    __syncthreads();
    bf16x8 a0 = *(bf16x8*)&As[wm*32 + frow][fk];
    bf16x8 a1 = *(bf16x8*)&As[wm*32 + 16 + frow][fk];
    #pragma unroll
    for (int nf = 0; nf < 4; ++nf){
      bf16x8 b = *(bf16x8*)&Bs[wn*64 + nf*16 + frow][fk];
      acc2[0][nf] = __builtin_amdgcn_mfma_f32_16x16x32_bf16(a0, b, acc2[0][nf], 0, 0, 0);
      acc2[1][nf] = __builtin_amdgcn_mfma_f32_16x16x32_bf16(a1, b, acc2[1][nf], 0, 0, 0);
    }
    __syncthreads();
  }
  // ----- epilogue: D row=(lane>>4)*4+reg, col=lane&15 -----
  #pragma unroll
  for (int nf = 0; nf < 4; ++nf){
    int gc = n0 + wn*64 + nf*16 + frow;
    float al = aL[gc], ar = aR[gc], bb = bias[gc];
    #pragma unroll
    for (int mf = 0; mf < 2; ++mf){
      #pragma unroll
      for (int reg = 0; reg < 4; ++reg){
        int gr = m0 + wm*32 + mf*16 + (lane >> 4)*4 + reg;
        float v = invdeg[gr]*al*acc1[mf][nf][reg] + ar*acc2[mf][nf][reg] + bb;
        H[(size_t)gr*256 + gc] = fmaxf(v, 0.f);
      }
    }
  }
}

// ---------------- layer-2 GEMM + log_softmax: one wave per target row ----------------
__global__ void gemm2_logsoftmax(const float* __restrict__ agg2, const uint32_t* __restrict__ packedH,
                                 const float* __restrict__ Bcat2, const float* __restrict__ bias,
                                 float* __restrict__ out){
  int t = blockIdx.x;
  int lane = threadIdx.x;       // 64
  __shared__ float av[512];
  for (int k = lane; k < 256; k += 64) av[k] = agg2[(size_t)t*256 + k];
  const uint32_t* pr = packedH + (size_t)t*16;
  for (int k = lane; k < 256; k += 64){
    int w = k >> 5, b = k & 31;
    av[256 + k] = (float)((pr[w]>>b)&1) - (float)((pr[8+w]>>b)&1);
  }
  __syncthreads();
  bool active = lane < 41;
  float acc = active ? bias[lane] : 0.f;
  for (int k = 0; k < 512; ++k){
    float bw = active ? Bcat2[k*41 + lane] : 0.f;
    acc += av[k] * bw;
  }
  float v = active ? acc : -INFINITY;
  float m = v;
  #pragma unroll
  for (int off = 32; off; off >>= 1) m = fmaxf(m, __shfl_xor(m, off));
  float e = active ? expf(v - m) : 0.f;
  float ssum = e;
  #pragma unroll
  for (int off = 32; off; off >>= 1) ssum += __shfl_xor(ssum, off);
  if (active) out[(size_t)t*41 + lane] = v - m - logf(ssum);
}

extern "C" void kernel_launch(void* const* d_in, const int* in_sizes, int n_in,
                              void* d_out, int out_size, void* d_ws, size_t ws_size,
                              hipStream_t stream){
  (void)n_in; (void)out_size; (void)ws_size;
  const float* x   = (const float*)d_in[0];
  const int*   ei1 = (const int*)d_in[1];
  const int*   ei2 = (const int*)d_in[2];
  const float* W1l = (const float*)d_in[5];
  const float* W1r = (const float*)d_in[6];
  const float* b1  = (const float*)d_in[7];
  const float* W2l = (const float*)d_in[8];
  const float* W2r = (const float*)d_in[9];
  const float* b2  = (const float*)d_in[10];
  float* out = (float*)d_out;

  const int FIN = 602, N1 = 11264, NB = 1024;
  const int N0 = in_sizes[0] / FIN;
  const int E1 = in_sizes[1] / 2;
  const int E2 = in_sizes[2] / 2;

  char* wsb = (char*)d_ws;
  size_t off = 0;
  auto carve = [&](size_t bytes)->void*{
    void* p = wsb + off;
    off = (off + bytes + 255) & ~(size_t)255;
    return p;
  };
  uint32_t* packedX = (uint32_t*)carve((size_t)N0*40*4);
  uint32_t* packedH = (uint32_t*)carve((size_t)N1*16*4);
  unsigned short* Sx = (unsigned short*)carve((size_t)N1*608*2);
  float* invdeg1 = (float*)carve((size_t)N1*4);
  float* h     = (float*)carve((size_t)N1*256*4);
  float* agg2  = (float*)carve((size_t)NB*256*4);
  unsigned short* bsgn = (unsigned short*)carve((size_t)256*1216*2);
  float* Bcat2 = (float*)carve((size_t)512*41*4);
  float* aL  = (float*)carve(256*4);
  float* aR  = (float*)carve(256*4);
  float* a2L = (float*)carve(64*4);
  float* a2R = (float*)carve(64*4);
  int* deg1  = (int*)carve((size_t)N1*4);
  int* rs1   = (int*)carve((size_t)(N1+1)*4);
  int* cur1  = (int*)carve((size_t)N1*4);
  int* esrc1 = (int*)carve((size_t)E1*4);
  int* deg2  = (int*)carve((size_t)NB*4);
  int* rs2   = (int*)carve((size_t)(NB+1)*4);
  int* cur2  = (int*)carve((size_t)NB*4);
  int* esrc2 = (int*)carve((size_t)E2*4);

  // weights: alphas (1 launch), sign matrices (2)
  prep_alpha<<<594, 256, 0, stream>>>(W1l, W1r, W2l, W2r, aL, aR, a2L, a2R);
  fill_bsgn<<<CDIV(256*1216, 256), 256, 0, stream>>>(W1l, W1r, bsgn);
  fill_bcat2<<<CDIV(512*41, 256), 256, 0, stream>>>(W2l, W2r, a2L, a2R, Bcat2);

  // norm_bin(x) -> packed signs (single pass over 705 MB)
  pack_v2<602,10,20><<<CDIV(N0, 4), 256, 0, stream>>>(x, packedX, N0);

  // CSR for both edge sets (4 launches total)
  zero_i32<<<CDIV(N1+NB, 256), 256, 0, stream>>>(deg1, N1 + NB);   // deg1,deg2 carved adjacent? no -> zero separately below
  zero_i32<<<CDIV(NB, 256), 256, 0, stream>>>(deg2, NB);
  count_both<<<CDIV(E1+E2, 256), 256, 0, stream>>>(ei1 + E1, E1, deg1, ei2 + E2, E2, deg2);
  scan2_kernel<<<2, 1024, 0, stream>>>(deg1, rs1, cur1, N1, deg2, rs2, cur2, NB);
  fill_both<<<CDIV(E1+E2, 256), 256, 0, stream>>>(ei1, ei1 + E1, E1, cur1, esrc1,
                                                  ei2, ei2 + E2, E2, cur2, esrc2);

  // layer 1: integer sign-sum (bf16-exact) + invdeg
  aggregate_bf16<19,20,40,608><<<N1, 64, 0, stream>>>(packedX, rs1, esrc1, Sx, invdeg1);

  // h = relu(invdeg*aL*(S@sgnWl^T) + aR*(sgnX@sgnWr^T) + b1) on MFMA
  gemm1_mfma<<<dim3(2, 176), 256, 0, stream>>>(Sx, packedX, bsgn, invdeg1, aL, aR, b1, h);

  // norm_bin(h) -> packed signs
  pack_v2<256,4,8><<<CDIV(N1, 4), 256, 0, stream>>>(h, packedH, N1);

  // layer 2 aggregate + tiny fused GEMM/log_softmax
  aggregate_f32<8,8,16,256><<<NB, 64, 0, stream>>>(packedH, rs2, esrc2, agg2);
  gemm2_logsoftmax<<<NB, 64, 0, stream>>>(agg2, packedH, Bcat2, b2, out);
}

// Round 4
// 309.950 us; speedup vs baseline: 2.7042x; 1.0981x over previous
//
#include <hip/hip_runtime.h>
#include <hip/hip_bf16.h>
#include <cstdint>
#include <cstddef>

#define CDIV(a,b) (((a)+(b)-1)/(b))

using bf16x8 = __attribute__((ext_vector_type(8))) short;
using f32x4  = __attribute__((ext_vector_type(4))) float;

struct __align__(8) F4 { float x, y, z, w; };
struct __align__(8) F2 { float x, y; };

__device__ __forceinline__ unsigned short sgn_bf16(float s){
  return (s > 0.f) ? 0x3F80u : ((s < 0.f) ? 0xBF80u : 0u);
}

// packed-order -> true column maps (permutation lives ONLY in weight-fill kernels)
// x-plane: 20 words. w<16: g=w>>3, wr=w&7, j=wr>>1, half=wr&1, lane=32*half+b, col=256g+4*lane+j
//          w in [16,20): j=w-16, col=512+4*b+j (valid < 602)
__device__ __forceinline__ int colX(int k){
  int w = k >> 5, b = k & 31;
  if (w < 16){
    int g = w >> 3, wr = w & 7;
    int j = wr >> 1, half = wr & 1;
    return 256*g + 4*(32*half + b) + j;
  }
  int j = w - 16;
  int c = 512 + 4*b + j;
  return (c < 602) ? c : -1;
}
// h-plane: 8 words. j=w>>1, half=w&1, col=4*(32*half+b)+j
__device__ __forceinline__ int colH(int k){
  int w = k >> 5, b = k & 31;
  int j = w >> 1, half = w & 1;
  return 4*(32*half + b) + j;
}

// ---------------- L0: alphas + zero degs + bsgn (sign of W1, permuted, bf16) ----------------
// blocks [0,594): alpha rows; [594,642): zero degB (12288 ints); [642,1922): bsgn 256x1280
__global__ void prep_all(const float* __restrict__ W1l, const float* __restrict__ W1r,
                         const float* __restrict__ W2l, const float* __restrict__ W2r,
                         float* __restrict__ aL, float* __restrict__ aR,
                         float* __restrict__ a2L, float* __restrict__ a2R,
                         int* __restrict__ degB, int ndeg,
                         unsigned short* __restrict__ bsgn){
  int r = blockIdx.x;
  if (r < 594){
    const float* wr; float* dst; int K;
    if (r < 256){ wr = W1l + (size_t)r*602; dst = aL + r; K = 602; }
    else if (r < 512){ int q = r-256; wr = W1r + (size_t)q*602; dst = aR + q; K = 602; }
    else if (r < 553){ int q = r-512; wr = W2l + (size_t)q*256; dst = a2L + q; K = 256; }
    else { int q = r-553; wr = W2r + (size_t)q*256; dst = a2R + q; K = 256; }
    float s = 0.f;
    for (int k = threadIdx.x; k < K; k += blockDim.x) s += fabsf(wr[k]);
    #pragma unroll
    for (int off = 32; off; off >>= 1) s += __shfl_xor(s, off);
    __shared__ float red[4];
    int wid = threadIdx.x >> 6, lane = threadIdx.x & 63;
    if (lane == 0) red[wid] = s;
    __syncthreads();
    if (threadIdx.x == 0) *dst = (red[0]+red[1]+red[2]+red[3]) / (float)K;
  } else if (r < 642){
    int i = (r - 594)*256 + threadIdx.x;
    if (i < ndeg) degB[i] = 0;
  } else {
    int idx = (r - 642)*256 + threadIdx.x;
    if (idx < 256*1280){
      int o = idx / 1280, k = idx - o*1280;
      float v = 0.f;
      if (k < 640){ int c = colX(k);       if (c >= 0) v = W1l[(size_t)o*602 + c]; }
      else        { int c = colX(k - 640); if (c >= 0) v = W1r[(size_t)o*602 + c]; }
      bsgn[idx] = sgn_bf16(v);
    }
  }
}

// ---------------- L1: pack(x) float4 + edge-degree count ----------------
// pack blocks: 4 rows/block (4 waves). count blocks appended.
__global__ void packx_count(const float* __restrict__ X, uint32_t* __restrict__ P, int nrows,
                            const int* __restrict__ d1, int E1, int* __restrict__ deg1,
                            const int* __restrict__ d2, int E2, int* __restrict__ deg2,
                            int packBlocks){
  if ((int)blockIdx.x >= packBlocks){
    int e = ((int)blockIdx.x - packBlocks)*blockDim.x + threadIdx.x;
    if (e < E1) atomicAdd(&deg1[d1[e]], 1);
    else if (e < E1 + E2) atomicAdd(&deg2[d2[e - E1]], 1);
    return;
  }
  const int row = blockIdx.x*4 + (threadIdx.x >> 6);
  const int lane = threadIdx.x & 63;
  if (row >= nrows) return;
  const float* xr = X + (size_t)row * 602;
  F4 v0 = *(const F4*)&xr[4*lane];
  F4 v1 = *(const F4*)&xr[256 + 4*lane];
  F4 v2 = {0.f,0.f,0.f,0.f};
  if (lane < 22) v2 = *(const F4*)&xr[512 + 4*lane];
  else if (lane == 22){ F2 t = *(const F2*)&xr[600]; v2.x = t.x; v2.y = t.y; }
  float s = v0.x+v0.y+v0.z+v0.w + v1.x+v1.y+v1.z+v1.w + v2.x+v2.y+v2.z+v2.w;
  #pragma unroll
  for (int off = 32; off; off >>= 1) s += __shfl_xor(s, off);
  const float mean = s / 602.f;
  uint32_t wpos[20], wneg[20];
  {
    float d0 = v0.x - mean, d1v = v0.y - mean, d2v = v0.z - mean, d3 = v0.w - mean;
    unsigned long long b0 = __ballot(d0 > 0.f), b1 = __ballot(d1v > 0.f),
                       b2 = __ballot(d2v > 0.f), b3 = __ballot(d3 > 0.f);
    wpos[0]=(uint32_t)b0; wpos[1]=(uint32_t)(b0>>32); wpos[2]=(uint32_t)b1; wpos[3]=(uint32_t)(b1>>32);
    wpos[4]=(uint32_t)b2; wpos[5]=(uint32_t)(b2>>32); wpos[6]=(uint32_t)b3; wpos[7]=(uint32_t)(b3>>32);
    b0 = __ballot(d0 < 0.f); b1 = __ballot(d1v < 0.f); b2 = __ballot(d2v < 0.f); b3 = __ballot(d3 < 0.f);
    wneg[0]=(uint32_t)b0; wneg[1]=(uint32_t)(b0>>32); wneg[2]=(uint32_t)b1; wneg[3]=(uint32_t)(b1>>32);
    wneg[4]=(uint32_t)b2; wneg[5]=(uint32_t)(b2>>32); wneg[6]=(uint32_t)b3; wneg[7]=(uint32_t)(b3>>32);
  }
  {
    float d0 = v1.x - mean, d1v = v1.y - mean, d2v = v1.z - mean, d3 = v1.w - mean;
    unsigned long long b0 = __ballot(d0 > 0.f), b1 = __ballot(d1v > 0.f),
                       b2 = __ballot(d2v > 0.f), b3 = __ballot(d3 > 0.f);
    wpos[8]=(uint32_t)b0; wpos[9]=(uint32_t)(b0>>32); wpos[10]=(uint32_t)b1; wpos[11]=(uint32_t)(b1>>32);
    wpos[12]=(uint32_t)b2; wpos[13]=(uint32_t)(b2>>32); wpos[14]=(uint32_t)b3; wpos[15]=(uint32_t)(b3>>32);
    b0 = __ballot(d0 < 0.f); b1 = __ballot(d1v < 0.f); b2 = __ballot(d2v < 0.f); b3 = __ballot(d3 < 0.f);
    wneg[8]=(uint32_t)b0; wneg[9]=(uint32_t)(b0>>32); wneg[10]=(uint32_t)b1; wneg[11]=(uint32_t)(b1>>32);
    wneg[12]=(uint32_t)b2; wneg[13]=(uint32_t)(b2>>32); wneg[14]=(uint32_t)b3; wneg[15]=(uint32_t)(b3>>32);
  }
  {
    int base = 4*lane;
    float d0 = v2.x - mean, d1v = v2.y - mean, d2v = v2.z - mean, d3 = v2.w - mean;
    wpos[16] = (uint32_t)__ballot((base+0 < 90) && (d0 > 0.f));
    wpos[17] = (uint32_t)__ballot((base+1 < 90) && (d1v > 0.f));
    wpos[18] = (uint32_t)__ballot((base+2 < 90) && (d2v > 0.f));
    wpos[19] = (uint32_t)__ballot((base+3 < 90) && (d3 > 0.f));
    wneg[16] = (uint32_t)__ballot((base+0 < 90) && (d0 < 0.f));
    wneg[17] = (uint32_t)__ballot((base+1 < 90) && (d1v < 0.f));
    wneg[18] = (uint32_t)__ballot((base+2 < 90) && (d2v < 0.f));
    wneg[19] = (uint32_t)__ballot((base+3 < 90) && (d3 < 0.f));
  }
  if (lane == 0){
    uint32_t* pr = P + (size_t)row * 40;
    #pragma unroll
    for (int q = 0; q < 5; ++q){
      uint4 a; a.x = wpos[4*q]; a.y = wpos[4*q+1]; a.z = wpos[4*q+2]; a.w = wpos[4*q+3];
      *(uint4*)&pr[4*q] = a;
      uint4 b; b.x = wneg[4*q]; b.y = wneg[4*q+1]; b.z = wneg[4*q+2]; b.w = wneg[4*q+3];
      *(uint4*)&pr[20 + 4*q] = b;
    }
  }
}

// ---------------- L2: dual scan (+cur copy) + Bcat2 fill (permuted) ----------------
__global__ void scan_bcat(const int* __restrict__ deg1, int* __restrict__ rs1, int* __restrict__ cur1, int n1,
                          const int* __restrict__ deg2, int* __restrict__ rs2, int* __restrict__ cur2, int n2,
                          const float* __restrict__ W2l, const float* __restrict__ W2r,
                          const float* __restrict__ a2L, const float* __restrict__ a2R,
                          float* __restrict__ Bcat2){
  if (blockIdx.x < 2){
    const int* deg = blockIdx.x ? deg2 : deg1;
    int* rs  = blockIdx.x ? rs2  : rs1;
    int* cur = blockIdx.x ? cur2 : cur1;
    int n    = blockIdx.x ? n2   : n1;
    __shared__ int partial[1024];
    int tid = threadIdx.x;
    int per = CDIV(n, 1024);
    int begin = tid*per; if (begin > n) begin = n;
    int end = begin + per; if (end > n) end = n;
    int s = 0;
    for (int i = begin; i < end; ++i) s += deg[i];
    partial[tid] = s;
    __syncthreads();
    for (int off = 1; off < 1024; off <<= 1){
      int add = (tid >= off) ? partial[tid-off] : 0;
      __syncthreads();
      partial[tid] += add;
      __syncthreads();
    }
    int prefix = (tid == 0) ? 0 : partial[tid-1];
    for (int i = begin; i < end; ++i){ rs[i] = prefix; cur[i] = prefix; prefix += deg[i]; }
    if (tid == 1023) rs[n] = prefix;
  } else {
    int idx = (blockIdx.x - 2)*1024 + threadIdx.x;
    if (idx < 512*41){
      int o = idx % 41, k = idx / 41;
      int c = (k < 256) ? colH(k) : colH(k - 256);
      float w = (k < 256) ? W2l[(size_t)o*256 + c] : W2r[(size_t)o*256 + c];
      float a = (k < 256) ? a2L[o] : a2R[o];
      float sg = (w > 0.f) ? 1.f : ((w < 0.f) ? -1.f : 0.f);
      Bcat2[idx] = a * sg;
    }
  }
}

// ---------------- L3: CSR fill (both) ----------------
__global__ void fill_both(const int* __restrict__ s1, const int* __restrict__ d1, int E1,
                          int* __restrict__ cur1, int* __restrict__ esrc1,
                          const int* __restrict__ s2, const int* __restrict__ d2, int E2,
                          int* __restrict__ cur2, int* __restrict__ esrc2){
  int e = blockIdx.x*blockDim.x + threadIdx.x;
  if (e < E1){
    int p = atomicAdd(&cur1[d1[e]], 1);
    esrc1[p] = s1[e];
  } else if (e < E1 + E2){
    int q = e - E1;
    int p = atomicAdd(&cur2[d2[q]], 1);
    esrc2[p] = s2[q];
  }
}

// ---------------- L4: aggregate layer-1 (byte-SIMD -> bf16 S, packed order) ----------------
template<int WUSED, int HALF, int STRIDE, int KPAD>
__global__ void aggregate_bf16(const uint32_t* __restrict__ packed,
                               const int* __restrict__ rs, const int* __restrict__ esrc,
                               unsigned short* __restrict__ S, float* __restrict__ invdeg){
  const int t = blockIdx.x;
  const int lane = threadIdx.x;     // 64
  const int s0 = rs[t], s1 = rs[t+1];
  uint32_t p[8] = {0,0,0,0,0,0,0,0};
  uint32_t n[8] = {0,0,0,0,0,0,0,0};
  if (lane < WUSED){
    for (int e = s0; e < s1; ++e){
      const uint32_t* pr = packed + (size_t)esrc[e] * STRIDE;
      uint32_t wp = pr[lane];
      uint32_t wn = pr[HALF + lane];
      #pragma unroll
      for (int b = 0; b < 8; ++b){
        p[b] += (wp >> b) & 0x01010101u;
        n[b] += (wn >> b) & 0x01010101u;
      }
    }
  }
  if (lane == 0){
    int deg = s1 - s0;
    invdeg[t] = 1.f / (float)(deg > 0 ? deg : 1);
  }
  if (lane < WUSED){
    unsigned short* sr = S + (size_t)t * KPAD;
    #pragma unroll
    for (int b = 0; b < 8; ++b){
      #pragma unroll
      for (int k = 0; k < 4; ++k){
        int col = 32*lane + b + 8*k;
        int cnt = (int)((p[b] >> (8*k)) & 0xFF) - (int)((n[b] >> (8*k)) & 0xFF);
        float f = (float)cnt;
        sr[col] = (unsigned short)(__float_as_uint(f) >> 16);
      }
    }
  }
}

// ---------------- L5: layer-1 MFMA GEMM (K = 640 + 640, packed order both sides) ----------------
__global__ __launch_bounds__(256) void gemm1_mfma(
    const unsigned short* __restrict__ Sx, const uint32_t* __restrict__ packedX,
    const unsigned short* __restrict__ bsgn, const float* __restrict__ invdeg,
    const float* __restrict__ aL, const float* __restrict__ aR,
    const float* __restrict__ bias, float* __restrict__ H){
  __shared__ __align__(16) unsigned short As[64][40];
  __shared__ __align__(16) unsigned short Bs[128][40];
  const int tid = threadIdx.x;
  const int lane = tid & 63, wid = tid >> 6;
  const int wm = wid & 1, wn = wid >> 1;
  const int m0 = blockIdx.y * 64, n0 = blockIdx.x * 128;
  const int sArow = tid >> 2, sAk = (tid & 3) * 8;
  const int sBcol = tid >> 1, sBk = (tid & 1) * 16;
  const int frow = lane & 15, fk = (lane >> 4) * 8;
  f32x4 acc1[2][4], acc2[2][4];
  #pragma unroll
  for (int i = 0; i < 2; ++i)
    #pragma unroll
    for (int j = 0; j < 4; ++j){ f32x4 z = {0.f,0.f,0.f,0.f}; acc1[i][j] = z; acc2[i][j] = z; }

  const unsigned short* SxRow = Sx + (size_t)(m0 + sArow) * 640;
  const uint32_t* pxRow = packedX + (size_t)(m0 + sArow) * 40;
  const unsigned short* bsgnRow = bsgn + (size_t)(n0 + sBcol) * 1280;

  // segment 1: A = S (bf16-exact integers)
  for (int kc = 0; kc < 640; kc += 32){
    *(bf16x8*)&As[sArow][sAk] = *(const bf16x8*)&SxRow[kc + sAk];
    *(bf16x8*)&Bs[sBcol][sBk]     = *(const bf16x8*)&bsgnRow[kc + sBk];
    *(bf16x8*)&Bs[sBcol][sBk + 8] = *(const bf16x8*)&bsgnRow[kc + sBk + 8];
    __syncthreads();
    bf16x8 a0 = *(bf16x8*)&As[wm*32 + frow][fk];
    bf16x8 a1 = *(bf16x8*)&As[wm*32 + 16 + frow][fk];
    #pragma unroll
    for (int nf = 0; nf < 4; ++nf){
      bf16x8 b = *(bf16x8*)&Bs[wn*64 + nf*16 + frow][fk];
      acc1[0][nf] = __builtin_amdgcn_mfma_f32_16x16x32_bf16(a0, b, acc1[0][nf], 0, 0, 0);
      acc1[1][nf] = __builtin_amdgcn_mfma_f32_16x16x32_bf16(a1, b, acc1[1][nf], 0, 0, 0);
    }
    __syncthreads();
  }
  // segment 2: A = sign bits of packedX (packed-linear order)
  for (int kc = 0; kc < 640; kc += 32){
    int w = kc >> 5;
    {
      uint32_t wp = pxRow[w];
      uint32_t wq = pxRow[20 + w];
      unsigned short tmp[8];
      #pragma unroll
      for (int j = 0; j < 8; ++j){
        int b_ = sAk + j;
        tmp[j] = ((wp >> b_) & 1) ? 0x3F80u : (((wq >> b_) & 1) ? 0xBF80u : 0u);
      }
      *(bf16x8*)&As[sArow][sAk] = *(bf16x8*)tmp;
    }
    *(bf16x8*)&Bs[sBcol][sBk]     = *(const bf16x8*)&bsgnRow[640 + kc + sBk];
    *(bf16x8*)&Bs[sBcol][sBk + 8] = *(const bf16x8*)&bsgnRow[640 + kc + sBk + 8];
    __syncthreads();
    bf16x8 a0 = *(bf16x8*)&As[wm*32 + frow][fk];
    bf16x8 a1 = *(bf16x8*)&As[wm*32 + 16 + frow][fk];
    #pragma unroll
    for (int nf = 0; nf < 4; ++nf){
      bf16x8 b = *(bf16x8*)&Bs[wn*64 + nf*16 + frow][fk];
      acc2[0][nf] = __builtin_amdgcn_mfma_f32_16x16x32_bf16(a0, b, acc2[0][nf], 0, 0, 0);
      acc2[1][nf] = __builtin_amdgcn_mfma_f32_16x16x32_bf16(a1, b, acc2[1][nf], 0, 0, 0);
    }
    __syncthreads();
  }
  #pragma unroll
  for (int nf = 0; nf < 4; ++nf){
    int gc = n0 + wn*64 + nf*16 + frow;
    float al = aL[gc], ar = aR[gc], bb = bias[gc];
    #pragma unroll
    for (int mf = 0; mf < 2; ++mf){
      #pragma unroll
      for (int reg = 0; reg < 4; ++reg){
        int gr = m0 + wm*32 + mf*16 + (lane >> 4)*4 + reg;
        float v = invdeg[gr]*al*acc1[mf][nf][reg] + ar*acc2[mf][nf][reg] + bb;
        H[(size_t)gr*256 + gc] = fmaxf(v, 0.f);
      }
    }
  }
}

// ---------------- L6: pack(h) — one float4/lane ----------------
__global__ void pack_h(const float* __restrict__ H, uint32_t* __restrict__ P, int nrows){
  const int row = blockIdx.x*4 + (threadIdx.x >> 6);
  const int lane = threadIdx.x & 63;
  if (row >= nrows) return;
  const float* hr = H + (size_t)row * 256;
  float4 v = *(const float4*)&hr[4*lane];
  float s = v.x + v.y + v.z + v.w;
  #pragma unroll
  for (int off = 32; off; off >>= 1) s += __shfl_xor(s, off);
  const float mean = s / 256.f;
  float d0 = v.x - mean, d1v = v.y - mean, d2v = v.z - mean, d3 = v.w - mean;
  uint32_t wpos[8], wneg[8];
  unsigned long long b0 = __ballot(d0 > 0.f), b1 = __ballot(d1v > 0.f),
                     b2 = __ballot(d2v > 0.f), b3 = __ballot(d3 > 0.f);
  wpos[0]=(uint32_t)b0; wpos[1]=(uint32_t)(b0>>32); wpos[2]=(uint32_t)b1; wpos[3]=(uint32_t)(b1>>32);
  wpos[4]=(uint32_t)b2; wpos[5]=(uint32_t)(b2>>32); wpos[6]=(uint32_t)b3; wpos[7]=(uint32_t)(b3>>32);
  b0 = __ballot(d0 < 0.f); b1 = __ballot(d1v < 0.f); b2 = __ballot(d2v < 0.f); b3 = __ballot(d3 < 0.f);
  wneg[0]=(uint32_t)b0; wneg[1]=(uint32_t)(b0>>32); wneg[2]=(uint32_t)b1; wneg[3]=(uint32_t)(b1>>32);
  wneg[4]=(uint32_t)b2; wneg[5]=(uint32_t)(b2>>32); wneg[6]=(uint32_t)b3; wneg[7]=(uint32_t)(b3>>32);
  if (lane == 0){
    uint32_t* pr = P + (size_t)row * 16;
    *(uint4*)&pr[0]  = make_uint4(wpos[0], wpos[1], wpos[2], wpos[3]);
    *(uint4*)&pr[4]  = make_uint4(wpos[4], wpos[5], wpos[6], wpos[7]);
    *(uint4*)&pr[8]  = make_uint4(wneg[0], wneg[1], wneg[2], wneg[3]);
    *(uint4*)&pr[12] = make_uint4(wneg[4], wneg[5], wneg[6], wneg[7]);
  }
}

// ---------------- L7: fused layer-2 aggregate + GEMM + log_softmax ----------------
__global__ void agg_gemm2(const uint32_t* __restrict__ packedH,
                          const int* __restrict__ rs, const int* __restrict__ esrc,
                          const float* __restrict__ Bcat2, const float* __restrict__ bias,
                          float* __restrict__ out){
  const int t = blockIdx.x;
  const int lane = threadIdx.x;   // 64
  __shared__ float av[512];
  const int s0 = rs[t], s1 = rs[t+1];
  uint32_t p[8] = {0,0,0,0,0,0,0,0};
  uint32_t n[8] = {0,0,0,0,0,0,0,0};
  if (lane < 8){
    for (int e = s0; e < s1; ++e){
      const uint32_t* pr = packedH + (size_t)esrc[e] * 16;
      uint32_t wp = pr[lane];
      uint32_t wn = pr[8 + lane];
      #pragma unroll
      for (int b = 0; b < 8; ++b){
        p[b] += (wp >> b) & 0x01010101u;
        n[b] += (wn >> b) & 0x01010101u;
      }
    }
    int deg = s1 - s0;
    float inv = 1.f / (float)(deg > 0 ? deg : 1);
    #pragma unroll
    for (int b = 0; b < 8; ++b){
      #pragma unroll
      for (int k = 0; k < 4; ++k){
        int col = 32*lane + b + 8*k;
        int cnt = (int)((p[b] >> (8*k)) & 0xFF) - (int)((n[b] >> (8*k)) & 0xFF);
        av[col] = (float)cnt * inv;
      }
    }
  }
  const uint32_t* pr = packedH + (size_t)t * 16;
  for (int k = lane; k < 256; k += 64){
    int w = k >> 5, b = k & 31;
    av[256 + k] = (float)((pr[w] >> b) & 1) - (float)((pr[8 + w] >> b) & 1);
  }
  __syncthreads();
  bool active = lane < 41;
  float acc = active ? bias[lane] : 0.f;
  for (int k = 0; k < 512; ++k){
    float bw = active ? Bcat2[k*41 + lane] : 0.f;
    acc += av[k] * bw;
  }
  float v = active ? acc : -INFINITY;
  float m = v;
  #pragma unroll
  for (int off = 32; off; off >>= 1) m = fmaxf(m, __shfl_xor(m, off));
  float e = active ? expf(v - m) : 0.f;
  float ssum = e;
  #pragma unroll
  for (int off = 32; off; off >>= 1) ssum += __shfl_xor(ssum, off);
  if (active) out[(size_t)t*41 + lane] = v - m - logf(ssum);
}

extern "C" void kernel_launch(void* const* d_in, const int* in_sizes, int n_in,
                              void* d_out, int out_size, void* d_ws, size_t ws_size,
                              hipStream_t stream){
  (void)n_in; (void)out_size; (void)ws_size;
  const float* x   = (const float*)d_in[0];
  const int*   ei1 = (const int*)d_in[1];
  const int*   ei2 = (const int*)d_in[2];
  const float* W1l = (const float*)d_in[5];
  const float* W1r = (const float*)d_in[6];
  const float* b1  = (const float*)d_in[7];
  const float* W2l = (const float*)d_in[8];
  const float* W2r = (const float*)d_in[9];
  const float* b2  = (const float*)d_in[10];
  float* out = (float*)d_out;

  const int FIN = 602, N1 = 11264, NB = 1024;
  const int N0 = in_sizes[0] / FIN;
  const int E1 = in_sizes[1] / 2;
  const int E2 = in_sizes[2] / 2;

  char* wsb = (char*)d_ws;
  size_t off = 0;
  auto carve = [&](size_t bytes)->void*{
    void* p = wsb + off;
    off = (off + bytes + 255) & ~(size_t)255;
    return p;
  };
  uint32_t* packedX = (uint32_t*)carve((size_t)N0*40*4);
  uint32_t* packedH = (uint32_t*)carve((size_t)N1*16*4);
  unsigned short* Sx = (unsigned short*)carve((size_t)N1*640*2);
  float* invdeg1 = (float*)carve((size_t)N1*4);
  float* h     = (float*)carve((size_t)N1*256*4);
  unsigned short* bsgn = (unsigned short*)carve((size_t)256*1280*2);
  float* Bcat2 = (float*)carve((size_t)512*41*4);
  float* aL  = (float*)carve(256*4);
  float* aR  = (float*)carve(256*4);
  float* a2L = (float*)carve(64*4);
  float* a2R = (float*)carve(64*4);
  int* degB  = (int*)carve((size_t)(N1+NB)*4);   // deg1 | deg2 contiguous
  int* deg1  = degB;
  int* deg2  = degB + N1;
  int* rs1   = (int*)carve((size_t)(N1+1)*4);
  int* cur1  = (int*)carve((size_t)N1*4);
  int* esrc1 = (int*)carve((size_t)E1*4);
  int* rs2   = (int*)carve((size_t)(NB+1)*4);
  int* cur2  = (int*)carve((size_t)NB*4);
  int* esrc2 = (int*)carve((size_t)E2*4);

  const int packBlocks = CDIV(N0, 4);
  const int cntBlocks  = CDIV(E1 + E2, 256);

  // L0: alphas + zero degs + bsgn
  prep_all<<<1922, 256, 0, stream>>>(W1l, W1r, W2l, W2r, aL, aR, a2L, a2R,
                                     degB, N1 + NB, bsgn);
  // L1: pack(x) + degree count
  packx_count<<<packBlocks + cntBlocks, 256, 0, stream>>>(
      x, packedX, N0, ei1 + E1, E1, deg1, ei2 + E2, E2, deg2, packBlocks);
  // L2: scans (+cur) + Bcat2
  scan_bcat<<<2 + CDIV(512*41, 1024), 1024, 0, stream>>>(
      deg1, rs1, cur1, N1, deg2, rs2, cur2, NB, W2l, W2r, a2L, a2R, Bcat2);
  // L3: CSR fill
  fill_both<<<cntBlocks, 256, 0, stream>>>(ei1, ei1 + E1, E1, cur1, esrc1,
                                           ei2, ei2 + E2, E2, cur2, esrc2);
  // L4: layer-1 aggregate (bf16-exact integer S)
  aggregate_bf16<20,20,40,640><<<N1, 64, 0, stream>>>(packedX, rs1, esrc1, Sx, invdeg1);
  // L5: layer-1 MFMA GEMM + bias + relu
  gemm1_mfma<<<dim3(2, 176), 256, 0, stream>>>(Sx, packedX, bsgn, invdeg1, aL, aR, b1, h);
  // L6: pack(h)
  pack_h<<<CDIV(N1, 4), 256, 0, stream>>>(h, packedH, N1);
  // L7: fused layer-2 aggregate + GEMM + log_softmax
  agg_gemm2<<<NB, 64, 0, stream>>>(packedH, rs2, esrc2, Bcat2, b2, out);
}

// Round 5
// 282.024 us; speedup vs baseline: 2.9719x; 1.0990x over previous
//
#include <hip/hip_runtime.h>
#include <hip/hip_bf16.h>
#include <cstdint>
#include <cstddef>

#define CDIV(a,b) (((a)+(b)-1)/(b))

using bf16x8 = __attribute__((ext_vector_type(8))) short;
using f32x4  = __attribute__((ext_vector_type(4))) float;

struct __align__(8) F4 { float x, y, z, w; };
struct __align__(8) F2 { float x, y; };

__device__ __forceinline__ unsigned short sgn_bf16(float s){
  return (s > 0.f) ? 0x3F80u : ((s < 0.f) ? 0xBF80u : 0u);
}

// packed-order -> true column maps (permutation lives ONLY in weight-fill kernels)
__device__ __forceinline__ int colX(int k){
  int w = k >> 5, b = k & 31;
  if (w < 16){
    int g = w >> 3, wr = w & 7;
    int j = wr >> 1, half = wr & 1;
    return 256*g + 4*(32*half + b) + j;
  }
  int j = w - 16;
  int c = 512 + 4*b + j;
  return (c < 602) ? c : -1;
}
__device__ __forceinline__ int colH(int k){
  int w = k >> 5, b = k & 31;
  int j = w >> 1, half = w & 1;
  return 4*(32*half + b) + j;
}

// ---------------- L0: alphas + zero degs + bsgn + mask init ----------------
// [0,594): alphas; [594,642): zero degB(12288); [642,1922): bsgn 256x1280;
// [1922,1922+maskBlocks): mask[i] = (i < N1)
__global__ void prep_all(const float* __restrict__ W1l, const float* __restrict__ W1r,
                         const float* __restrict__ W2l, const float* __restrict__ W2r,
                         float* __restrict__ aL, float* __restrict__ aR,
                         float* __restrict__ a2L, float* __restrict__ a2R,
                         int* __restrict__ degB, int ndeg,
                         unsigned short* __restrict__ bsgn,
                         unsigned char* __restrict__ mask, int n0, int n1){
  int r = blockIdx.x;
  if (r < 594){
    const float* wr; float* dst; int K;
    if (r < 256){ wr = W1l + (size_t)r*602; dst = aL + r; K = 602; }
    else if (r < 512){ int q = r-256; wr = W1r + (size_t)q*602; dst = aR + q; K = 602; }
    else if (r < 553){ int q = r-512; wr = W2l + (size_t)q*256; dst = a2L + q; K = 256; }
    else { int q = r-553; wr = W2r + (size_t)q*256; dst = a2R + q; K = 256; }
    float s = 0.f;
    for (int k = threadIdx.x; k < K; k += blockDim.x) s += fabsf(wr[k]);
    #pragma unroll
    for (int off = 32; off; off >>= 1) s += __shfl_xor(s, off);
    __shared__ float red[4];
    int wid = threadIdx.x >> 6, lane = threadIdx.x & 63;
    if (lane == 0) red[wid] = s;
    __syncthreads();
    if (threadIdx.x == 0) *dst = (red[0]+red[1]+red[2]+red[3]) / (float)K;
  } else if (r < 642){
    int i = (r - 594)*256 + threadIdx.x;
    if (i < ndeg) degB[i] = 0;
  } else if (r < 1922){
    int idx = (r - 642)*256 + threadIdx.x;
    if (idx < 256*1280){
      int o = idx / 1280, k = idx - o*1280;
      float v = 0.f;
      if (k < 640){ int c = colX(k);       if (c >= 0) v = W1l[(size_t)o*602 + c]; }
      else        { int c = colX(k - 640); if (c >= 0) v = W1r[(size_t)o*602 + c]; }
      bsgn[idx] = sgn_bf16(v);
    }
  } else {
    int i = (r - 1922)*256 + threadIdx.x;
    if (i < n0) mask[i] = (i < n1) ? 1 : 0;
  }
}

// ---------------- L0.5: mark used src rows + count degrees (both edge sets) ----------------
__global__ void mark_count(const int* __restrict__ s1, const int* __restrict__ d1, int E1,
                           unsigned char* __restrict__ mask, int* __restrict__ deg1,
                           const int* __restrict__ d2, int E2, int* __restrict__ deg2){
  int e = blockIdx.x*blockDim.x + threadIdx.x;
  if (e < E1){
    mask[s1[e]] = 1;
    atomicAdd(&deg1[d1[e]], 1);
  } else if (e < E1 + E2){
    atomicAdd(&deg2[d2[e - E1]], 1);
  }
}

// ---------------- L1: masked pack(x), float4 loads ----------------
__global__ void pack_masked(const float* __restrict__ X, uint32_t* __restrict__ P, int nrows,
                            const unsigned char* __restrict__ mask){
  const int row = blockIdx.x*4 + (threadIdx.x >> 6);
  const int lane = threadIdx.x & 63;
  if (row >= nrows) return;
  if (!mask[row]) return;
  const float* xr = X + (size_t)row * 602;
  F4 v0 = *(const F4*)&xr[4*lane];
  F4 v1 = *(const F4*)&xr[256 + 4*lane];
  F4 v2 = {0.f,0.f,0.f,0.f};
  if (lane < 22) v2 = *(const F4*)&xr[512 + 4*lane];
  else if (lane == 22){ F2 t = *(const F2*)&xr[600]; v2.x = t.x; v2.y = t.y; }
  float s = v0.x+v0.y+v0.z+v0.w + v1.x+v1.y+v1.z+v1.w + v2.x+v2.y+v2.z+v2.w;
  #pragma unroll
  for (int off = 32; off; off >>= 1) s += __shfl_xor(s, off);
  const float mean = s / 602.f;
  uint32_t wpos[20], wneg[20];
  {
    float d0 = v0.x - mean, d1v = v0.y - mean, d2v = v0.z - mean, d3 = v0.w - mean;
    unsigned long long b0 = __ballot(d0 > 0.f), b1 = __ballot(d1v > 0.f),
                       b2 = __ballot(d2v > 0.f), b3 = __ballot(d3 > 0.f);
    wpos[0]=(uint32_t)b0; wpos[1]=(uint32_t)(b0>>32); wpos[2]=(uint32_t)b1; wpos[3]=(uint32_t)(b1>>32);
    wpos[4]=(uint32_t)b2; wpos[5]=(uint32_t)(b2>>32); wpos[6]=(uint32_t)b3; wpos[7]=(uint32_t)(b3>>32);
    b0 = __ballot(d0 < 0.f); b1 = __ballot(d1v < 0.f); b2 = __ballot(d2v < 0.f); b3 = __ballot(d3 < 0.f);
    wneg[0]=(uint32_t)b0; wneg[1]=(uint32_t)(b0>>32); wneg[2]=(uint32_t)b1; wneg[3]=(uint32_t)(b1>>32);
    wneg[4]=(uint32_t)b2; wneg[5]=(uint32_t)(b2>>32); wneg[6]=(uint32_t)b3; wneg[7]=(uint32_t)(b3>>32);
  }
  {
    float d0 = v1.x - mean, d1v = v1.y - mean, d2v = v1.z - mean, d3 = v1.w - mean;
    unsigned long long b0 = __ballot(d0 > 0.f), b1 = __ballot(d1v > 0.f),
                       b2 = __ballot(d2v > 0.f), b3 = __ballot(d3 > 0.f);
    wpos[8]=(uint32_t)b0; wpos[9]=(uint32_t)(b0>>32); wpos[10]=(uint32_t)b1; wpos[11]=(uint32_t)(b1>>32);
    wpos[12]=(uint32_t)b2; wpos[13]=(uint32_t)(b2>>32); wpos[14]=(uint32_t)b3; wpos[15]=(uint32_t)(b3>>32);
    b0 = __ballot(d0 < 0.f); b1 = __ballot(d1v < 0.f); b2 = __ballot(d2v < 0.f); b3 = __ballot(d3 < 0.f);
    wneg[8]=(uint32_t)b0; wneg[9]=(uint32_t)(b0>>32); wneg[10]=(uint32_t)b1; wneg[11]=(uint32_t)(b1>>32);
    wneg[12]=(uint32_t)b2; wneg[13]=(uint32_t)(b2>>32); wneg[14]=(uint32_t)b3; wneg[15]=(uint32_t)(b3>>32);
  }
  {
    int base = 4*lane;
    float d0 = v2.x - mean, d1v = v2.y - mean, d2v = v2.z - mean, d3 = v2.w - mean;
    wpos[16] = (uint32_t)__ballot((base+0 < 90) && (d0 > 0.f));
    wpos[17] = (uint32_t)__ballot((base+1 < 90) && (d1v > 0.f));
    wpos[18] = (uint32_t)__ballot((base+2 < 90) && (d2v > 0.f));
    wpos[19] = (uint32_t)__ballot((base+3 < 90) && (d3 > 0.f));
    wneg[16] = (uint32_t)__ballot((base+0 < 90) && (d0 < 0.f));
    wneg[17] = (uint32_t)__ballot((base+1 < 90) && (d1v < 0.f));
    wneg[18] = (uint32_t)__ballot((base+2 < 90) && (d2v < 0.f));
    wneg[19] = (uint32_t)__ballot((base+3 < 90) && (d3 < 0.f));
  }
  if (lane == 0){
    uint32_t* pr = P + (size_t)row * 40;
    #pragma unroll
    for (int q = 0; q < 5; ++q){
      uint4 a; a.x = wpos[4*q]; a.y = wpos[4*q+1]; a.z = wpos[4*q+2]; a.w = wpos[4*q+3];
      *(uint4*)&pr[4*q] = a;
      uint4 b; b.x = wneg[4*q]; b.y = wneg[4*q+1]; b.z = wneg[4*q+2]; b.w = wneg[4*q+3];
      *(uint4*)&pr[20 + 4*q] = b;
    }
  }
}

// ---------------- L2: dual scan (+cur copy) + Bcat2 fill ----------------
__global__ void scan_bcat(const int* __restrict__ deg1, int* __restrict__ rs1, int* __restrict__ cur1, int n1,
                          const int* __restrict__ deg2, int* __restrict__ rs2, int* __restrict__ cur2, int n2,
                          const float* __restrict__ W2l, const float* __restrict__ W2r,
                          const float* __restrict__ a2L, const float* __restrict__ a2R,
                          float* __restrict__ Bcat2){
  if (blockIdx.x < 2){
    const int* deg = blockIdx.x ? deg2 : deg1;
    int* rs  = blockIdx.x ? rs2  : rs1;
    int* cur = blockIdx.x ? cur2 : cur1;
    int n    = blockIdx.x ? n2   : n1;
    __shared__ int partial[1024];
    int tid = threadIdx.x;
    int per = CDIV(n, 1024);
    int begin = tid*per; if (begin > n) begin = n;
    int end = begin + per; if (end > n) end = n;
    int s = 0;
    for (int i = begin; i < end; ++i) s += deg[i];
    partial[tid] = s;
    __syncthreads();
    for (int off = 1; off < 1024; off <<= 1){
      int add = (tid >= off) ? partial[tid-off] : 0;
      __syncthreads();
      partial[tid] += add;
      __syncthreads();
    }
    int prefix = (tid == 0) ? 0 : partial[tid-1];
    for (int i = begin; i < end; ++i){ rs[i] = prefix; cur[i] = prefix; prefix += deg[i]; }
    if (tid == 1023) rs[n] = prefix;
  } else {
    int idx = (blockIdx.x - 2)*1024 + threadIdx.x;
    if (idx < 512*41){
      int o = idx % 41, k = idx / 41;
      int c = (k < 256) ? colH(k) : colH(k - 256);
      float w = (k < 256) ? W2l[(size_t)o*256 + c] : W2r[(size_t)o*256 + c];
      float a = (k < 256) ? a2L[o] : a2R[o];
      float sg = (w > 0.f) ? 1.f : ((w < 0.f) ? -1.f : 0.f);
      Bcat2[idx] = a * sg;
    }
  }
}

// ---------------- L3: CSR fill (both) ----------------
__global__ void fill_both(const int* __restrict__ s1, const int* __restrict__ d1, int E1,
                          int* __restrict__ cur1, int* __restrict__ esrc1,
                          const int* __restrict__ s2, const int* __restrict__ d2, int E2,
                          int* __restrict__ cur2, int* __restrict__ esrc2){
  int e = blockIdx.x*blockDim.x + threadIdx.x;
  if (e < E1){
    int p = atomicAdd(&cur1[d1[e]], 1);
    esrc1[p] = s1[e];
  } else if (e < E1 + E2){
    int q = e - E1;
    int p = atomicAdd(&cur2[d2[q]], 1);
    esrc2[p] = s2[q];
  }
}

// ---------------- L4: aggregate layer-1 (byte-SIMD -> bf16 S, packed order) ----------------
template<int WUSED, int HALF, int STRIDE, int KPAD>
__global__ void aggregate_bf16(const uint32_t* __restrict__ packed,
                               const int* __restrict__ rs, const int* __restrict__ esrc,
                               unsigned short* __restrict__ S, float* __restrict__ invdeg){
  const int t = blockIdx.x;
  const int lane = threadIdx.x;     // 64
  const int s0 = rs[t], s1 = rs[t+1];
  uint32_t p[8] = {0,0,0,0,0,0,0,0};
  uint32_t n[8] = {0,0,0,0,0,0,0,0};
  if (lane < WUSED){
    for (int e = s0; e < s1; ++e){
      const uint32_t* pr = packed + (size_t)esrc[e] * STRIDE;
      uint32_t wp = pr[lane];
      uint32_t wn = pr[HALF + lane];
      #pragma unroll
      for (int b = 0; b < 8; ++b){
        p[b] += (wp >> b) & 0x01010101u;
        n[b] += (wn >> b) & 0x01010101u;
      }
    }
  }
  if (lane == 0){
    int deg = s1 - s0;
    invdeg[t] = 1.f / (float)(deg > 0 ? deg : 1);
  }
  if (lane < WUSED){
    unsigned short* sr = S + (size_t)t * KPAD;
    #pragma unroll
    for (int b = 0; b < 8; ++b){
      #pragma unroll
      for (int k = 0; k < 4; ++k){
        int col = 32*lane + b + 8*k;
        int cnt = (int)((p[b] >> (8*k)) & 0xFF) - (int)((n[b] >> (8*k)) & 0xFF);
        float f = (float)cnt;
        sr[col] = (unsigned short)(__float_as_uint(f) >> 16);
      }
    }
  }
}

// ---------------- L5: layer-1 MFMA GEMM (32x256 tile) + fused norm_bin pack ----------------
// Grid: N1/32 = 352 blocks x 256 thr (4 waves, all on N). Each block owns 32 FULL rows
// -> computes H in regs, relu, row-mean + ballots in epilogue, writes packedH directly.
// h never touches global memory.
__global__ __launch_bounds__(256) void gemm1_fused(
    const unsigned short* __restrict__ Sx, const uint32_t* __restrict__ packedX,
    const unsigned short* __restrict__ bsgn, const float* __restrict__ invdeg,
    const float* __restrict__ aL, const float* __restrict__ aR,
    const float* __restrict__ bias, uint32_t* __restrict__ packedH){
  // LDS union: staging (As 32x40 + Bs 256x40 shorts = 23040 B) vs Hs 32x264 f32 (33792 B)
  __shared__ __align__(16) char smem[33792];
  unsigned short (*As)[40] = (unsigned short (*)[40])smem;
  unsigned short (*Bs)[40] = (unsigned short (*)[40])(smem + 32*40*2);
  float (*Hs)[264] = (float (*)[264])smem;

  const int tid = threadIdx.x;
  const int lane = tid & 63, wid = tid >> 6;      // wid = N-wave (cols wid*64..+63)
  const int m0 = blockIdx.x * 32;
  const int frow = lane & 15, fk = (lane >> 4) * 8;
  const int sRow = tid >> 3, sK = (tid & 7) * 4;  // A staging: 8 thr/row, 4 shorts each

  f32x4 acc1[2][4], acc2[2][4];
  #pragma unroll
  for (int i = 0; i < 2; ++i)
    #pragma unroll
    for (int j = 0; j < 4; ++j){ f32x4 z = {0.f,0.f,0.f,0.f}; acc1[i][j] = z; acc2[i][j] = z; }

  const unsigned short* SxRow = Sx + (size_t)(m0 + sRow) * 640;
  const uint32_t* pxRow = packedX + (size_t)(m0 + sRow) * 40;
  const unsigned short* bsgnCol = bsgn + (size_t)tid * 1280;   // col = tid (n0 = 0)

  // segment 1: A = S (bf16-exact integers), k in [0,640)
  for (int kc = 0; kc < 640; kc += 32){
    *(uint2*)&As[sRow][sK] = *(const uint2*)&SxRow[kc + sK];
    *(bf16x8*)&Bs[tid][0]  = *(const bf16x8*)&bsgnCol[kc];
    *(bf16x8*)&Bs[tid][8]  = *(const bf16x8*)&bsgnCol[kc + 8];
    *(bf16x8*)&Bs[tid][16] = *(const bf16x8*)&bsgnCol[kc + 16];
    *(bf16x8*)&Bs[tid][24] = *(const bf16x8*)&bsgnCol[kc + 24];
    __syncthreads();
    bf16x8 a0 = *(bf16x8*)&As[frow][fk];
    bf16x8 a1 = *(bf16x8*)&As[16 + frow][fk];
    #pragma unroll
    for (int nf = 0; nf < 4; ++nf){
      bf16x8 b = *(bf16x8*)&Bs[wid*64 + nf*16 + frow][fk];
      acc1[0][nf] = __builtin_amdgcn_mfma_f32_16x16x32_bf16(a0, b, acc1[0][nf], 0, 0, 0);
      acc1[1][nf] = __builtin_amdgcn_mfma_f32_16x16x32_bf16(a1, b, acc1[1][nf], 0, 0, 0);
    }
    __syncthreads();
  }
  // segment 2: A = sign bits of packedX
  for (int kc = 0; kc < 640; kc += 32){
    int w = kc >> 5;
    {
      uint32_t wp = pxRow[w];
      uint32_t wq = pxRow[20 + w];
      union { unsigned short u[4]; uint2 v; } tmp;
      #pragma unroll
      for (int j = 0; j < 4; ++j){
        int b_ = sK + j;
        tmp.u[j] = ((wp >> b_) & 1) ? 0x3F80u : (((wq >> b_) & 1) ? 0xBF80u : 0u);
      }
      *(uint2*)&As[sRow][sK] = tmp.v;
    }
    *(bf16x8*)&Bs[tid][0]  = *(const bf16x8*)&bsgnCol[640 + kc];
    *(bf16x8*)&Bs[tid][8]  = *(const bf16x8*)&bsgnCol[640 + kc + 8];
    *(bf16x8*)&Bs[tid][16] = *(const bf16x8*)&bsgnCol[640 + kc + 16];
    *(bf16x8*)&Bs[tid][24] = *(const bf16x8*)&bsgnCol[640 + kc + 24];
    __syncthreads();
    bf16x8 a0 = *(bf16x8*)&As[frow][fk];
    bf16x8 a1 = *(bf16x8*)&As[16 + frow][fk];
    #pragma unroll
    for (int nf = 0; nf < 4; ++nf){
      bf16x8 b = *(bf16x8*)&Bs[wid*64 + nf*16 + frow][fk];
      acc2[0][nf] = __builtin_amdgcn_mfma_f32_16x16x32_bf16(a0, b, acc2[0][nf], 0, 0, 0);
      acc2[1][nf] = __builtin_amdgcn_mfma_f32_16x16x32_bf16(a1, b, acc2[1][nf], 0, 0, 0);
    }
    __syncthreads();
  }

  // epilogue: scale + bias + relu -> Hs (overwrites staging LDS; safe after last barrier)
  #pragma unroll
  for (int nf = 0; nf < 4; ++nf){
    int gc = wid*64 + nf*16 + frow;
    float al = aL[gc], ar = aR[gc], bb = bias[gc];
    #pragma unroll
    for (int mf = 0; mf < 2; ++mf){
      #pragma unroll
      for (int reg = 0; reg < 4; ++reg){
        int lr = mf*16 + (lane >> 4)*4 + reg;
        float v = invdeg[m0 + lr]*al*acc1[mf][nf][reg] + ar*acc2[mf][nf][reg] + bb;
        Hs[lr][gc] = fmaxf(v, 0.f);
      }
    }
  }
  __syncthreads();

  // fused norm_bin pack: wave wid packs rows wid*8 .. wid*8+7 (layout == colH)
  for (int r = 0; r < 8; ++r){
    int row = wid*8 + r;
    float4 v = *(const float4*)&Hs[row][4*lane];
    float s = v.x + v.y + v.z + v.w;
    #pragma unroll
    for (int off = 32; off; off >>= 1) s += __shfl_xor(s, off);
    float mean = s * (1.f/256.f);
    float d0 = v.x - mean, d1v = v.y - mean, d2v = v.z - mean, d3 = v.w - mean;
    unsigned long long b0 = __ballot(d0 > 0.f), b1 = __ballot(d1v > 0.f),
                       b2 = __ballot(d2v > 0.f), b3 = __ballot(d3 > 0.f);
    uint32_t wpos[8], wneg[8];
    wpos[0]=(uint32_t)b0; wpos[1]=(uint32_t)(b0>>32); wpos[2]=(uint32_t)b1; wpos[3]=(uint32_t)(b1>>32);
    wpos[4]=(uint32_t)b2; wpos[5]=(uint32_t)(b2>>32); wpos[6]=(uint32_t)b3; wpos[7]=(uint32_t)(b3>>32);
    b0 = __ballot(d0 < 0.f); b1 = __ballot(d1v < 0.f); b2 = __ballot(d2v < 0.f); b3 = __ballot(d3 < 0.f);
    wneg[0]=(uint32_t)b0; wneg[1]=(uint32_t)(b0>>32); wneg[2]=(uint32_t)b1; wneg[3]=(uint32_t)(b1>>32);
    wneg[4]=(uint32_t)b2; wneg[5]=(uint32_t)(b2>>32); wneg[6]=(uint32_t)b3; wneg[7]=(uint32_t)(b3>>32);
    if (lane == 0){
      uint32_t* pr = packedH + (size_t)(m0 + row) * 16;
      *(uint4*)&pr[0]  = make_uint4(wpos[0], wpos[1], wpos[2], wpos[3]);
      *(uint4*)&pr[4]  = make_uint4(wpos[4], wpos[5], wpos[6], wpos[7]);
      *(uint4*)&pr[8]  = make_uint4(wneg[0], wneg[1], wneg[2], wneg[3]);
      *(uint4*)&pr[12] = make_uint4(wneg[4], wneg[5], wneg[6], wneg[7]);
    }
  }
}

// ---------------- L6: fused layer-2 aggregate + GEMM + log_softmax ----------------
__global__ void agg_gemm2(const uint32_t* __restrict__ packedH,
                          const int* __restrict__ rs, const int* __restrict__ esrc,
                          const float* __restrict__ Bcat2, const float* __restrict__ bias,
                          float* __restrict__ out){
  const int t = blockIdx.x;
  const int lane = threadIdx.x;   // 64
  __shared__ float av[512];
  const int s0 = rs[t], s1 = rs[t+1];
  uint32_t p[8] = {0,0,0,0,0,0,0,0};
  uint32_t n[8] = {0,0,0,0,0,0,0,0};
  if (lane < 8){
    for (int e = s0; e < s1; ++e){
      const uint32_t* pr = packedH + (size_t)esrc[e] * 16;
      uint32_t wp = pr[lane];
      uint32_t wn = pr[8 + lane];
      #pragma unroll
      for (int b = 0; b < 8; ++b){
        p[b] += (wp >> b) & 0x01010101u;
        n[b] += (wn >> b) & 0x01010101u;
      }
    }
    int deg = s1 - s0;
    float inv = 1.f / (float)(deg > 0 ? deg : 1);
    #pragma unroll
    for (int b = 0; b < 8; ++b){
      #pragma unroll
      for (int k = 0; k < 4; ++k){
        int col = 32*lane + b + 8*k;
        int cnt = (int)((p[b] >> (8*k)) & 0xFF) - (int)((n[b] >> (8*k)) & 0xFF);
        av[col] = (float)cnt * inv;
      }
    }
  }
  const uint32_t* pr = packedH + (size_t)t * 16;
  for (int k = lane; k < 256; k += 64){
    int w = k >> 5, b = k & 31;
    av[256 + k] = (float)((pr[w] >> b) & 1) - (float)((pr[8 + w] >> b) & 1);
  }
  __syncthreads();
  bool active = lane < 41;
  float acc = active ? bias[lane] : 0.f;
  for (int k = 0; k < 512; ++k){
    float bw = active ? Bcat2[k*41 + lane] : 0.f;
    acc += av[k] * bw;
  }
  float v = active ? acc : -INFINITY;
  float m = v;
  #pragma unroll
  for (int off = 32; off; off >>= 1) m = fmaxf(m, __shfl_xor(m, off));
  float e = active ? expf(v - m) : 0.f;
  float ssum = e;
  #pragma unroll
  for (int off = 32; off; off >>= 1) ssum += __shfl_xor(ssum, off);
  if (active) out[(size_t)t*41 + lane] = v - m - logf(ssum);
}

extern "C" void kernel_launch(void* const* d_in, const int* in_sizes, int n_in,
                              void* d_out, int out_size, void* d_ws, size_t ws_size,
                              hipStream_t stream){
  (void)n_in; (void)out_size; (void)ws_size;
  const float* x   = (const float*)d_in[0];
  const int*   ei1 = (const int*)d_in[1];
  const int*   ei2 = (const int*)d_in[2];
  const float* W1l = (const float*)d_in[5];
  const float* W1r = (const float*)d_in[6];
  const float* b1  = (const float*)d_in[7];
  const float* W2l = (const float*)d_in[8];
  const float* W2r = (const float*)d_in[9];
  const float* b2  = (const float*)d_in[10];
  float* out = (float*)d_out;

  const int FIN = 602, N1 = 11264, NB = 1024;
  const int N0 = in_sizes[0] / FIN;
  const int E1 = in_sizes[1] / 2;
  const int E2 = in_sizes[2] / 2;

  char* wsb = (char*)d_ws;
  size_t off = 0;
  auto carve = [&](size_t bytes)->void*{
    void* p = wsb + off;
    off = (off + bytes + 255) & ~(size_t)255;
    return p;
  };
  uint32_t* packedX = (uint32_t*)carve((size_t)N0*40*4);
  uint32_t* packedH = (uint32_t*)carve((size_t)N1*16*4);
  unsigned short* Sx = (unsigned short*)carve((size_t)N1*640*2);
  float* invdeg1 = (float*)carve((size_t)N1*4);
  unsigned short* bsgn = (unsigned short*)carve((size_t)256*1280*2);
  float* Bcat2 = (float*)carve((size_t)512*41*4);
  float* aL  = (float*)carve(256*4);
  float* aR  = (float*)carve(256*4);
  float* a2L = (float*)carve(64*4);
  float* a2R = (float*)carve(64*4);
  unsigned char* mask = (unsigned char*)carve((size_t)N0);
  int* degB  = (int*)carve((size_t)(N1+NB)*4);
  int* deg1  = degB;
  int* deg2  = degB + N1;
  int* rs1   = (int*)carve((size_t)(N1+1)*4);
  int* cur1  = (int*)carve((size_t)N1*4);
  int* esrc1 = (int*)carve((size_t)E1*4);
  int* rs2   = (int*)carve((size_t)(NB+1)*4);
  int* cur2  = (int*)carve((size_t)NB*4);
  int* esrc2 = (int*)carve((size_t)E2*4);

  const int maskBlocks = CDIV(N0, 256);
  const int cntBlocks  = CDIV(E1 + E2, 256);

  // L0: alphas + zero degs + bsgn + mask init
  prep_all<<<1922 + maskBlocks, 256, 0, stream>>>(
      W1l, W1r, W2l, W2r, aL, aR, a2L, a2R, degB, N1 + NB, bsgn, mask, N0, N1);
  // L0.5: mark used rows + degree count
  mark_count<<<cntBlocks, 256, 0, stream>>>(ei1, ei1 + E1, E1, mask, deg1,
                                            ei2 + E2, E2, deg2);
  // L1: masked pack(x)
  pack_masked<<<CDIV(N0, 4), 256, 0, stream>>>(x, packedX, N0, mask);
  // L2: scans (+cur) + Bcat2
  scan_bcat<<<2 + CDIV(512*41, 1024), 1024, 0, stream>>>(
      deg1, rs1, cur1, N1, deg2, rs2, cur2, NB, W2l, W2r, a2L, a2R, Bcat2);
  // L3: CSR fill
  fill_both<<<cntBlocks, 256, 0, stream>>>(ei1, ei1 + E1, E1, cur1, esrc1,
                                           ei2, ei2 + E2, E2, cur2, esrc2);
  // L4: layer-1 aggregate (bf16-exact integer S)
  aggregate_bf16<20,20,40,640><<<N1, 64, 0, stream>>>(packedX, rs1, esrc1, Sx, invdeg1);
  // L5: layer-1 MFMA GEMM + bias + relu + fused norm_bin pack (h never hits HBM)
  gemm1_fused<<<N1/32, 256, 0, stream>>>(Sx, packedX, bsgn, invdeg1, aL, aR, b1, packedH);
  // L6: fused layer-2 aggregate + GEMM + log_softmax
  agg_gemm2<<<NB, 64, 0, stream>>>(packedH, rs2, esrc2, Bcat2, b2, out);
}

// Round 6
// 277.275 us; speedup vs baseline: 3.0228x; 1.0171x over previous
//
#include <hip/hip_runtime.h>
#include <hip/hip_bf16.h>
#include <cstdint>
#include <cstddef>

#define CDIV(a,b) (((a)+(b)-1)/(b))

using bf16x8 = __attribute__((ext_vector_type(8))) short;
using f32x4  = __attribute__((ext_vector_type(4))) float;

struct __align__(8) F4 { float x, y, z, w; };
struct __align__(8) F2 { float x, y; };

__device__ __forceinline__ unsigned short sgn_bf16(float s){
  return (s > 0.f) ? 0x3F80u : ((s < 0.f) ? 0xBF80u : 0u);
}

// packed-order -> true column maps (permutation lives ONLY in weight-fill kernels)
__device__ __forceinline__ int colX(int k){
  int w = k >> 5, b = k & 31;
  if (w < 16){
    int g = w >> 3, wr = w & 7;
    int j = wr >> 1, half = wr & 1;
    return 256*g + 4*(32*half + b) + j;
  }
  int j = w - 16;
  int c = 512 + 4*b + j;
  return (c < 602) ? c : -1;
}
__device__ __forceinline__ int colH(int k){
  int w = k >> 5, b = k & 31;
  int j = w >> 1, half = w & 1;
  return 4*(32*half + b) + j;
}

// ---------------- L0: alphas + zero degs + bsgn + mask init ----------------
__global__ void prep_all(const float* __restrict__ W1l, const float* __restrict__ W1r,
                         const float* __restrict__ W2l, const float* __restrict__ W2r,
                         float* __restrict__ aL, float* __restrict__ aR,
                         float* __restrict__ a2L, float* __restrict__ a2R,
                         int* __restrict__ degB, int ndeg,
                         unsigned short* __restrict__ bsgn,
                         unsigned char* __restrict__ mask, int n0, int n1){
  int r = blockIdx.x;
  if (r < 594){
    const float* wr; float* dst; int K;
    if (r < 256){ wr = W1l + (size_t)r*602; dst = aL + r; K = 602; }
    else if (r < 512){ int q = r-256; wr = W1r + (size_t)q*602; dst = aR + q; K = 602; }
    else if (r < 553){ int q = r-512; wr = W2l + (size_t)q*256; dst = a2L + q; K = 256; }
    else { int q = r-553; wr = W2r + (size_t)q*256; dst = a2R + q; K = 256; }
    float s = 0.f;
    for (int k = threadIdx.x; k < K; k += blockDim.x) s += fabsf(wr[k]);
    #pragma unroll
    for (int off = 32; off; off >>= 1) s += __shfl_xor(s, off);
    __shared__ float red[4];
    int wid = threadIdx.x >> 6, lane = threadIdx.x & 63;
    if (lane == 0) red[wid] = s;
    __syncthreads();
    if (threadIdx.x == 0) *dst = (red[0]+red[1]+red[2]+red[3]) / (float)K;
  } else if (r < 642){
    int i = (r - 594)*256 + threadIdx.x;
    if (i < ndeg) degB[i] = 0;
  } else if (r < 1922){
    int idx = (r - 642)*256 + threadIdx.x;
    if (idx < 256*1280){
      int o = idx / 1280, k = idx - o*1280;
      float v = 0.f;
      if (k < 640){ int c = colX(k);       if (c >= 0) v = W1l[(size_t)o*602 + c]; }
      else        { int c = colX(k - 640); if (c >= 0) v = W1r[(size_t)o*602 + c]; }
      bsgn[idx] = sgn_bf16(v);
    }
  } else {
    int i = (r - 1922)*256 + threadIdx.x;
    if (i < n0) mask[i] = (i < n1) ? 1 : 0;
  }
}

// ---------------- L0.5: mark used src rows + count degrees ----------------
__global__ void mark_count(const int* __restrict__ s1, const int* __restrict__ d1, int E1,
                           unsigned char* __restrict__ mask, int* __restrict__ deg1,
                           const int* __restrict__ d2, int E2, int* __restrict__ deg2){
  int e = blockIdx.x*blockDim.x + threadIdx.x;
  if (e < E1){
    mask[s1[e]] = 1;
    atomicAdd(&deg1[d1[e]], 1);
  } else if (e < E1 + E2){
    atomicAdd(&deg2[d2[e - E1]], 1);
  }
}

// ---------------- L1: masked pack(x) + dual 256-thread scans + Bcat2 (merged roles) ----------------
__global__ void pack_scan_bcat(const float* __restrict__ X, uint32_t* __restrict__ P, int nrows,
                               const unsigned char* __restrict__ mask, int packBlocks,
                               const int* __restrict__ deg1, int* __restrict__ rs1, int* __restrict__ cur1, int n1c,
                               const int* __restrict__ deg2, int* __restrict__ rs2, int* __restrict__ cur2, int n2c,
                               const float* __restrict__ W2l, const float* __restrict__ W2r,
                               const float* __restrict__ a2L, const float* __restrict__ a2R,
                               float* __restrict__ Bcat2){
  __shared__ int partial[256];
  const int bid = blockIdx.x;
  if (bid >= packBlocks){
    int role = bid - packBlocks;
    if (role < 2){
      // 256-thread exclusive scan (+cur copy)
      const int* deg = role ? deg2 : deg1;
      int* rs  = role ? rs2  : rs1;
      int* cur = role ? cur2 : cur1;
      int n    = role ? n2c  : n1c;
      int tid = threadIdx.x;
      int per = CDIV(n, 256);
      int begin = tid*per; if (begin > n) begin = n;
      int end = begin + per; if (end > n) end = n;
      int s = 0;
      for (int i = begin; i < end; ++i) s += deg[i];
      partial[tid] = s;
      __syncthreads();
      for (int off = 1; off < 256; off <<= 1){
        int add = (tid >= off) ? partial[tid-off] : 0;
        __syncthreads();
        partial[tid] += add;
        __syncthreads();
      }
      int prefix = (tid == 0) ? 0 : partial[tid-1];
      for (int i = begin; i < end; ++i){ rs[i] = prefix; cur[i] = prefix; prefix += deg[i]; }
      if (tid == 255) rs[n] = prefix;
    } else {
      int idx = (role - 2)*256 + threadIdx.x;
      if (idx < 512*41){
        int o = idx % 41, k = idx / 41;
        int c = (k < 256) ? colH(k) : colH(k - 256);
        float w = (k < 256) ? W2l[(size_t)o*256 + c] : W2r[(size_t)o*256 + c];
        float a = (k < 256) ? a2L[o] : a2R[o];
        float sg = (w > 0.f) ? 1.f : ((w < 0.f) ? -1.f : 0.f);
        Bcat2[idx] = a * sg;
      }
    }
    return;
  }
  // ---- pack role ----
  const int row = bid*4 + (threadIdx.x >> 6);
  const int lane = threadIdx.x & 63;
  if (row >= nrows) return;
  if (!mask[row]) return;
  const float* xr = X + (size_t)row * 602;
  F4 v0 = *(const F4*)&xr[4*lane];
  F4 v1 = *(const F4*)&xr[256 + 4*lane];
  F4 v2 = {0.f,0.f,0.f,0.f};
  if (lane < 22) v2 = *(const F4*)&xr[512 + 4*lane];
  else if (lane == 22){ F2 t = *(const F2*)&xr[600]; v2.x = t.x; v2.y = t.y; }
  float s = v0.x+v0.y+v0.z+v0.w + v1.x+v1.y+v1.z+v1.w + v2.x+v2.y+v2.z+v2.w;
  #pragma unroll
  for (int off = 32; off; off >>= 1) s += __shfl_xor(s, off);
  const float mean = s / 602.f;
  uint32_t wpos[20], wneg[20];
  {
    float d0 = v0.x - mean, d1v = v0.y - mean, d2v = v0.z - mean, d3 = v0.w - mean;
    unsigned long long b0 = __ballot(d0 > 0.f), b1 = __ballot(d1v > 0.f),
                       b2 = __ballot(d2v > 0.f), b3 = __ballot(d3 > 0.f);
    wpos[0]=(uint32_t)b0; wpos[1]=(uint32_t)(b0>>32); wpos[2]=(uint32_t)b1; wpos[3]=(uint32_t)(b1>>32);
    wpos[4]=(uint32_t)b2; wpos[5]=(uint32_t)(b2>>32); wpos[6]=(uint32_t)b3; wpos[7]=(uint32_t)(b3>>32);
    b0 = __ballot(d0 < 0.f); b1 = __ballot(d1v < 0.f); b2 = __ballot(d2v < 0.f); b3 = __ballot(d3 < 0.f);
    wneg[0]=(uint32_t)b0; wneg[1]=(uint32_t)(b0>>32); wneg[2]=(uint32_t)b1; wneg[3]=(uint32_t)(b1>>32);
    wneg[4]=(uint32_t)b2; wneg[5]=(uint32_t)(b2>>32); wneg[6]=(uint32_t)b3; wneg[7]=(uint32_t)(b3>>32);
  }
  {
    float d0 = v1.x - mean, d1v = v1.y - mean, d2v = v1.z - mean, d3 = v1.w - mean;
    unsigned long long b0 = __ballot(d0 > 0.f), b1 = __ballot(d1v > 0.f),
                       b2 = __ballot(d2v > 0.f), b3 = __ballot(d3 > 0.f);
    wpos[8]=(uint32_t)b0; wpos[9]=(uint32_t)(b0>>32); wpos[10]=(uint32_t)b1; wpos[11]=(uint32_t)(b1>>32);
    wpos[12]=(uint32_t)b2; wpos[13]=(uint32_t)(b2>>32); wpos[14]=(uint32_t)b3; wpos[15]=(uint32_t)(b3>>32);
    b0 = __ballot(d0 < 0.f); b1 = __ballot(d1v < 0.f); b2 = __ballot(d2v < 0.f); b3 = __ballot(d3 < 0.f);
    wneg[8]=(uint32_t)b0; wneg[9]=(uint32_t)(b0>>32); wneg[10]=(uint32_t)b1; wneg[11]=(uint32_t)(b1>>32);
    wneg[12]=(uint32_t)b2; wneg[13]=(uint32_t)(b2>>32); wneg[14]=(uint32_t)b3; wneg[15]=(uint32_t)(b3>>32);
  }
  {
    int base = 4*lane;
    float d0 = v2.x - mean, d1v = v2.y - mean, d2v = v2.z - mean, d3 = v2.w - mean;
    wpos[16] = (uint32_t)__ballot((base+0 < 90) && (d0 > 0.f));
    wpos[17] = (uint32_t)__ballot((base+1 < 90) && (d1v > 0.f));
    wpos[18] = (uint32_t)__ballot((base+2 < 90) && (d2v > 0.f));
    wpos[19] = (uint32_t)__ballot((base+3 < 90) && (d3 > 0.f));
    wneg[16] = (uint32_t)__ballot((base+0 < 90) && (d0 < 0.f));
    wneg[17] = (uint32_t)__ballot((base+1 < 90) && (d1v < 0.f));
    wneg[18] = (uint32_t)__ballot((base+2 < 90) && (d2v < 0.f));
    wneg[19] = (uint32_t)__ballot((base+3 < 90) && (d3 < 0.f));
  }
  if (lane == 0){
    uint32_t* pr = P + (size_t)row * 40;
    #pragma unroll
    for (int q = 0; q < 5; ++q){
      uint4 a; a.x = wpos[4*q]; a.y = wpos[4*q+1]; a.z = wpos[4*q+2]; a.w = wpos[4*q+3];
      *(uint4*)&pr[4*q] = a;
      uint4 b; b.x = wneg[4*q]; b.y = wneg[4*q+1]; b.z = wneg[4*q+2]; b.w = wneg[4*q+3];
      *(uint4*)&pr[20 + 4*q] = b;
    }
  }
}

// ---------------- L2: CSR fill (both) ----------------
__global__ void fill_both(const int* __restrict__ s1, const int* __restrict__ d1, int E1,
                          int* __restrict__ cur1, int* __restrict__ esrc1,
                          const int* __restrict__ s2, const int* __restrict__ d2, int E2,
                          int* __restrict__ cur2, int* __restrict__ esrc2){
  int e = blockIdx.x*blockDim.x + threadIdx.x;
  if (e < E1){
    int p = atomicAdd(&cur1[d1[e]], 1);
    esrc1[p] = s1[e];
  } else if (e < E1 + E2){
    int q = e - E1;
    int p = atomicAdd(&cur2[d2[q]], 1);
    esrc2[p] = s2[q];
  }
}

// ---------------- L3: aggregate layer-1, 3 edges in flight (lanes = slot*20+w) ----------------
// Integer byte-SIMD counts; cross-slot combine via shfl; bf16-exact S out.
__global__ void aggregate_v3(const uint32_t* __restrict__ packed,
                             const int* __restrict__ rs, const int* __restrict__ esrc,
                             unsigned short* __restrict__ S, float* __restrict__ invdeg){
  const int t = blockIdx.x;
  const int lane = threadIdx.x;     // 64
  const int slot = lane / 20;       // 0..2 active, 3 = idle (lanes 60..63)
  const int w = lane - slot*20;
  const int s0 = rs[t], s1 = rs[t+1];
  const bool active = slot < 3;
  uint32_t p[8] = {0,0,0,0,0,0,0,0};
  uint32_t n[8] = {0,0,0,0,0,0,0,0};
  for (int base = s0; base < s1; base += 3){
    int e = base + slot;
    uint32_t wp = 0, wn = 0;
    if (active && e < s1){
      const uint32_t* pr = packed + (size_t)esrc[e] * 40;
      wp = pr[w];
      wn = pr[20 + w];
    }
    #pragma unroll
    for (int b = 0; b < 8; ++b){
      p[b] += (wp >> b) & 0x01010101u;
      n[b] += (wn >> b) & 0x01010101u;
    }
  }
  // combine slots: lanes 0..19 gather slot1 (lane+20) and slot2 (lane+40)
  #pragma unroll
  for (int b = 0; b < 8; ++b){
    p[b] += __shfl(p[b], lane + 20) + __shfl(p[b], lane + 40);
    n[b] += __shfl(n[b], lane + 20) + __shfl(n[b], lane + 40);
  }
  if (lane == 0){
    int deg = s1 - s0;
    invdeg[t] = 1.f / (float)(deg > 0 ? deg : 1);
  }
  if (lane < 20){
    unsigned short* sr = S + (size_t)t * 640;
    #pragma unroll
    for (int b = 0; b < 8; ++b){
      #pragma unroll
      for (int k = 0; k < 4; ++k){
        int col = 32*lane + b + 8*k;
        int cnt = (int)((p[b] >> (8*k)) & 0xFF) - (int)((n[b] >> (8*k)) & 0xFF);
        float f = (float)cnt;
        sr[col] = (unsigned short)(__float_as_uint(f) >> 16);
      }
    }
  }
}

// ---------------- L4: layer-1 MFMA GEMM (32x256 tile) + fused norm_bin pack ----------------
__global__ __launch_bounds__(256) void gemm1_fused(
    const unsigned short* __restrict__ Sx, const uint32_t* __restrict__ packedX,
    const unsigned short* __restrict__ bsgn, const float* __restrict__ invdeg,
    const float* __restrict__ aL, const float* __restrict__ aR,
    const float* __restrict__ bias, uint32_t* __restrict__ packedH){
  __shared__ __align__(16) char smem[33792];
  unsigned short (*As)[40] = (unsigned short (*)[40])smem;
  unsigned short (*Bs)[40] = (unsigned short (*)[40])(smem + 32*40*2);
  float (*Hs)[264] = (float (*)[264])smem;

  const int tid = threadIdx.x;
  const int lane = tid & 63, wid = tid >> 6;
  const int m0 = blockIdx.x * 32;
  const int frow = lane & 15, fk = (lane >> 4) * 8;
  const int sRow = tid >> 3, sK = (tid & 7) * 4;

  f32x4 acc1[2][4], acc2[2][4];
  #pragma unroll
  for (int i = 0; i < 2; ++i)
    #pragma unroll
    for (int j = 0; j < 4; ++j){ f32x4 z = {0.f,0.f,0.f,0.f}; acc1[i][j] = z; acc2[i][j] = z; }

  const unsigned short* SxRow = Sx + (size_t)(m0 + sRow) * 640;
  const uint32_t* pxRow = packedX + (size_t)(m0 + sRow) * 40;
  const unsigned short* bsgnCol = bsgn + (size_t)tid * 1280;

  for (int kc = 0; kc < 640; kc += 32){
    *(uint2*)&As[sRow][sK] = *(const uint2*)&SxRow[kc + sK];
    *(bf16x8*)&Bs[tid][0]  = *(const bf16x8*)&bsgnCol[kc];
    *(bf16x8*)&Bs[tid][8]  = *(const bf16x8*)&bsgnCol[kc + 8];
    *(bf16x8*)&Bs[tid][16] = *(const bf16x8*)&bsgnCol[kc + 16];
    *(bf16x8*)&Bs[tid][24] = *(const bf16x8*)&bsgnCol[kc + 24];
    __syncthreads();
    bf16x8 a0 = *(bf16x8*)&As[frow][fk];
    bf16x8 a1 = *(bf16x8*)&As[16 + frow][fk];
    #pragma unroll
    for (int nf = 0; nf < 4; ++nf){
      bf16x8 b = *(bf16x8*)&Bs[wid*64 + nf*16 + frow][fk];
      acc1[0][nf] = __builtin_amdgcn_mfma_f32_16x16x32_bf16(a0, b, acc1[0][nf], 0, 0, 0);
      acc1[1][nf] = __builtin_amdgcn_mfma_f32_16x16x32_bf16(a1, b, acc1[1][nf], 0, 0, 0);
    }
    __syncthreads();
  }
  for (int kc = 0; kc < 640; kc += 32){
    int w = kc >> 5;
    {
      uint32_t wp = pxRow[w];
      uint32_t wq = pxRow[20 + w];
      union { unsigned short u[4]; uint2 v; } tmp;
      #pragma unroll
      for (int j = 0; j < 4; ++j){
        int b_ = sK + j;
        tmp.u[j] = ((wp >> b_) & 1) ? 0x3F80u : (((wq >> b_) & 1) ? 0xBF80u : 0u);
      }
      *(uint2*)&As[sRow][sK] = tmp.v;
    }
    *(bf16x8*)&Bs[tid][0]  = *(const bf16x8*)&bsgnCol[640 + kc];
    *(bf16x8*)&Bs[tid][8]  = *(const bf16x8*)&bsgnCol[640 + kc + 8];
    *(bf16x8*)&Bs[tid][16] = *(const bf16x8*)&bsgnCol[640 + kc + 16];
    *(bf16x8*)&Bs[tid][24] = *(const bf16x8*)&bsgnCol[640 + kc + 24];
    __syncthreads();
    bf16x8 a0 = *(bf16x8*)&As[frow][fk];
    bf16x8 a1 = *(bf16x8*)&As[16 + frow][fk];
    #pragma unroll
    for (int nf = 0; nf < 4; ++nf){
      bf16x8 b = *(bf16x8*)&Bs[wid*64 + nf*16 + frow][fk];
      acc2[0][nf] = __builtin_amdgcn_mfma_f32_16x16x32_bf16(a0, b, acc2[0][nf], 0, 0, 0);
      acc2[1][nf] = __builtin_amdgcn_mfma_f32_16x16x32_bf16(a1, b, acc2[1][nf], 0, 0, 0);
    }
    __syncthreads();
  }

  #pragma unroll
  for (int nf = 0; nf < 4; ++nf){
    int gc = wid*64 + nf*16 + frow;
    float al = aL[gc], ar = aR[gc], bb = bias[gc];
    #pragma unroll
    for (int mf = 0; mf < 2; ++mf){
      #pragma unroll
      for (int reg = 0; reg < 4; ++reg){
        int lr = mf*16 + (lane >> 4)*4 + reg;
        float v = invdeg[m0 + lr]*al*acc1[mf][nf][reg] + ar*acc2[mf][nf][reg] + bb;
        Hs[lr][gc] = fmaxf(v, 0.f);
      }
    }
  }
  __syncthreads();

  for (int r = 0; r < 8; ++r){
    int row = wid*8 + r;
    float4 v = *(const float4*)&Hs[row][4*lane];
    float s = v.x + v.y + v.z + v.w;
    #pragma unroll
    for (int off = 32; off; off >>= 1) s += __shfl_xor(s, off);
    float mean = s * (1.f/256.f);
    float d0 = v.x - mean, d1v = v.y - mean, d2v = v.z - mean, d3 = v.w - mean;
    unsigned long long b0 = __ballot(d0 > 0.f), b1 = __ballot(d1v > 0.f),
                       b2 = __ballot(d2v > 0.f), b3 = __ballot(d3 > 0.f);
    uint32_t wpos[8], wneg[8];
    wpos[0]=(uint32_t)b0; wpos[1]=(uint32_t)(b0>>32); wpos[2]=(uint32_t)b1; wpos[3]=(uint32_t)(b1>>32);
    wpos[4]=(uint32_t)b2; wpos[5]=(uint32_t)(b2>>32); wpos[6]=(uint32_t)b3; wpos[7]=(uint32_t)(b3>>32);
    b0 = __ballot(d0 < 0.f); b1 = __ballot(d1v < 0.f); b2 = __ballot(d2v < 0.f); b3 = __ballot(d3 < 0.f);
    wneg[0]=(uint32_t)b0; wneg[1]=(uint32_t)(b0>>32); wneg[2]=(uint32_t)b1; wneg[3]=(uint32_t)(b1>>32);
    wneg[4]=(uint32_t)b2; wneg[5]=(uint32_t)(b2>>32); wneg[6]=(uint32_t)b3; wneg[7]=(uint32_t)(b3>>32);
    if (lane == 0){
      uint32_t* pr = packedH + (size_t)(m0 + row) * 16;
      *(uint4*)&pr[0]  = make_uint4(wpos[0], wpos[1], wpos[2], wpos[3]);
      *(uint4*)&pr[4]  = make_uint4(wpos[4], wpos[5], wpos[6], wpos[7]);
      *(uint4*)&pr[8]  = make_uint4(wneg[0], wneg[1], wneg[2], wneg[3]);
      *(uint4*)&pr[12] = make_uint4(wneg[4], wneg[5], wneg[6], wneg[7]);
    }
  }
}

// ---------------- L5: fused layer-2 aggregate (8 edges in flight) + GEMM + log_softmax ----------------
__global__ void agg_gemm2(const uint32_t* __restrict__ packedH,
                          const int* __restrict__ rs, const int* __restrict__ esrc,
                          const float* __restrict__ Bcat2, const float* __restrict__ bias,
                          float* __restrict__ out){
  const int t = blockIdx.x;
  const int lane = threadIdx.x;   // 64
  const int slot = lane >> 3, w = lane & 7;
  __shared__ float av[512];
  const int s0 = rs[t], s1 = rs[t+1];
  uint32_t p[8] = {0,0,0,0,0,0,0,0};
  uint32_t n[8] = {0,0,0,0,0,0,0,0};
  for (int base = s0; base < s1; base += 8){
    int e = base + slot;
    uint32_t wp = 0, wn = 0;
    if (e < s1){
      const uint32_t* pr = packedH + (size_t)esrc[e] * 16;
      wp = pr[w];
      wn = pr[8 + w];
    }
    #pragma unroll
    for (int b = 0; b < 8; ++b){
      p[b] += (wp >> b) & 0x01010101u;
      n[b] += (wn >> b) & 0x01010101u;
    }
  }
  #pragma unroll
  for (int b = 0; b < 8; ++b){
    p[b] += __shfl_xor(p[b], 8);  p[b] += __shfl_xor(p[b], 16);  p[b] += __shfl_xor(p[b], 32);
    n[b] += __shfl_xor(n[b], 8);  n[b] += __shfl_xor(n[b], 16);  n[b] += __shfl_xor(n[b], 32);
  }
  int deg = s1 - s0;
  float inv = 1.f / (float)(deg > 0 ? deg : 1);
  if (lane < 8){
    #pragma unroll
    for (int b = 0; b < 8; ++b){
      #pragma unroll
      for (int k = 0; k < 4; ++k){
        int col = 32*lane + b + 8*k;
        int cnt = (int)((p[b] >> (8*k)) & 0xFF) - (int)((n[b] >> (8*k)) & 0xFF);
        av[col] = (float)cnt * inv;
      }
    }
  }
  const uint32_t* pr = packedH + (size_t)t * 16;
  for (int k = lane; k < 256; k += 64){
    int wq = k >> 5, b = k & 31;
    av[256 + k] = (float)((pr[wq] >> b) & 1) - (float)((pr[8 + wq] >> b) & 1);
  }
  __syncthreads();
  bool activeO = lane < 41;
  float acc = activeO ? bias[lane] : 0.f;
  for (int k = 0; k < 512; ++k){
    float bw = activeO ? Bcat2[k*41 + lane] : 0.f;
    acc += av[k] * bw;
  }
  float v = activeO ? acc : -INFINITY;
  float m = v;
  #pragma unroll
  for (int off = 32; off; off >>= 1) m = fmaxf(m, __shfl_xor(m, off));
  float e = activeO ? expf(v - m) : 0.f;
  float ssum = e;
  #pragma unroll
  for (int off = 32; off; off >>= 1) ssum += __shfl_xor(ssum, off);
  if (activeO) out[(size_t)t*41 + lane] = v - m - logf(ssum);
}

extern "C" void kernel_launch(void* const* d_in, const int* in_sizes, int n_in,
                              void* d_out, int out_size, void* d_ws, size_t ws_size,
                              hipStream_t stream){
  (void)n_in; (void)out_size; (void)ws_size;
  const float* x   = (const float*)d_in[0];
  const int*   ei1 = (const int*)d_in[1];
  const int*   ei2 = (const int*)d_in[2];
  const float* W1l = (const float*)d_in[5];
  const float* W1r = (const float*)d_in[6];
  const float* b1  = (const float*)d_in[7];
  const float* W2l = (const float*)d_in[8];
  const float* W2r = (const float*)d_in[9];
  const float* b2  = (const float*)d_in[10];
  float* out = (float*)d_out;

  const int FIN = 602, N1 = 11264, NB = 1024;
  const int N0 = in_sizes[0] / FIN;
  const int E1 = in_sizes[1] / 2;
  const int E2 = in_sizes[2] / 2;

  char* wsb = (char*)d_ws;
  size_t off = 0;
  auto carve = [&](size_t bytes)->void*{
    void* p = wsb + off;
    off = (off + bytes + 255) & ~(size_t)255;
    return p;
  };
  uint32_t* packedX = (uint32_t*)carve((size_t)N0*40*4);
  uint32_t* packedH = (uint32_t*)carve((size_t)N1*16*4);
  unsigned short* Sx = (unsigned short*)carve((size_t)N1*640*2);
  float* invdeg1 = (float*)carve((size_t)N1*4);
  unsigned short* bsgn = (unsigned short*)carve((size_t)256*1280*2);
  float* Bcat2 = (float*)carve((size_t)512*41*4);
  float* aL  = (float*)carve(256*4);
  float* aR  = (float*)carve(256*4);
  float* a2L = (float*)carve(64*4);
  float* a2R = (float*)carve(64*4);
  unsigned char* mask = (unsigned char*)carve((size_t)N0);
  int* degB  = (int*)carve((size_t)(N1+NB)*4);
  int* deg1  = degB;
  int* deg2  = degB + N1;
  int* rs1   = (int*)carve((size_t)(N1+1)*4);
  int* cur1  = (int*)carve((size_t)N1*4);
  int* esrc1 = (int*)carve((size_t)E1*4);
  int* rs2   = (int*)carve((size_t)(NB+1)*4);
  int* cur2  = (int*)carve((size_t)NB*4);
  int* esrc2 = (int*)carve((size_t)E2*4);

  const int maskBlocks = CDIV(N0, 256);
  const int cntBlocks  = CDIV(E1 + E2, 256);
  const int packBlocks = CDIV(N0, 4);
  const int bcatBlocks = CDIV(512*41, 256);

  // L0: alphas + zero degs + bsgn + mask init
  prep_all<<<1922 + maskBlocks, 256, 0, stream>>>(
      W1l, W1r, W2l, W2r, aL, aR, a2L, a2R, degB, N1 + NB, bsgn, mask, N0, N1);
  // L0.5: mark used rows + degree count
  mark_count<<<cntBlocks, 256, 0, stream>>>(ei1, ei1 + E1, E1, mask, deg1,
                                            ei2 + E2, E2, deg2);
  // L1: masked pack(x) + dual scans + Bcat2 (independent roles, one launch)
  pack_scan_bcat<<<packBlocks + 2 + bcatBlocks, 256, 0, stream>>>(
      x, packedX, N0, mask, packBlocks,
      deg1, rs1, cur1, N1, deg2, rs2, cur2, NB,
      W2l, W2r, a2L, a2R, Bcat2);
  // L2: CSR fill
  fill_both<<<cntBlocks, 256, 0, stream>>>(ei1, ei1 + E1, E1, cur1, esrc1,
                                           ei2, ei2 + E2, E2, cur2, esrc2);
  // L3: layer-1 aggregate, 3 edges in flight
  aggregate_v3<<<N1, 64, 0, stream>>>(packedX, rs1, esrc1, Sx, invdeg1);
  // L4: layer-1 MFMA GEMM + bias + relu + fused norm_bin pack
  gemm1_fused<<<N1/32, 256, 0, stream>>>(Sx, packedX, bsgn, invdeg1, aL, aR, b1, packedH);
  // L5: fused layer-2 aggregate + GEMM + log_softmax
  agg_gemm2<<<NB, 64, 0, stream>>>(packedH, rs2, esrc2, Bcat2, b2, out);
}